// Round 11
// baseline (1618.419 us; speedup 1.0000x reference)
//
#include <hip/hip_runtime.h>

#define H 128
typedef unsigned short u16;
typedef __attribute__((ext_vector_type(8))) short bf16x8;
typedef __attribute__((ext_vector_type(4))) float f32x4;

#define NPC 200000
#define NAC 100000
#define NVC 10000
#define EWC 2000000
#define EPC 200000
#define ETOT 6400000
#define NDEG 710000
#define NPP 200064
#define NAP 100096
#define NVP 10112
#define TP 1563
#define TA 782
#define TV 79
#define CHUNKE 4096
#define NCHUNK ((ETOT + CHUNKE - 1) / CHUNKE)
#define XRANGE ((NDEG + 7) / 8)

__device__ __forceinline__ u16 f2b(float f) {
    unsigned u = __builtin_bit_cast(unsigned, f);
    unsigned r = (u + 0x7fff + ((u >> 16) & 1)) >> 16;
    return (u16)r;
}
__device__ __forceinline__ float b2f(u16 b) {
    unsigned u = ((unsigned)b) << 16;
    return __builtin_bit_cast(float, u);
}

// ---------------- cast f32 -> bf16 ----------------
__global__ void cast_kernel(const float* __restrict__ in, u16* __restrict__ out, long n4) {
    long stride = (long)gridDim.x * blockDim.x;
    for (long i = (long)blockIdx.x * blockDim.x + threadIdx.x; i < n4; i += stride) {
        float4 v = reinterpret_cast<const float4*>(in)[i];
        ushort4 o;
        o.x = f2b(v.x); o.y = f2b(v.y); o.z = f2b(v.z); o.w = f2b(v.w);
        reinterpret_cast<ushort4*>(out)[i] = o;
    }
}

// ---------------- pack weights into MFMA B-fragment layout (bf16) ----------------
// jobs m: 0-2: Wl[l,m]; 3: sum Wr[l,0..2]; 4: Wl[l,3]; 5: Wr[l,3]; 6: Wl[l,4]; 7: Wr[l,4]
__global__ void pack_kernel(const float* __restrict__ Wl, const float* __restrict__ Wr,
                            u16* __restrict__ out) {
    int tid = blockIdx.x * blockDim.x + threadIdx.x;  // 16*16384
    int e = tid & 16383;
    int job = tid >> 14;
    int l = job >> 3, m = job & 7;
    int lane = (e >> 3) & 63;
    int j = e & 7;
    int knb = e >> 9;  // 0..31
    int k = (knb >> 3) * 32 + ((lane >> 4) & 3) * 8 + j;
    int n = (knb & 7) * 16 + (lane & 15);
    long off = (long)k * H + n;
    float v;
    if (m < 3) v = Wl[((long)(l * 5 + m)) * (H * H) + off];
    else if (m == 3) v = Wr[((long)(l * 5 + 0)) * (H * H) + off] +
                         Wr[((long)(l * 5 + 1)) * (H * H) + off] +
                         Wr[((long)(l * 5 + 2)) * (H * H) + off];
    else if (m == 4) v = Wl[((long)(l * 5 + 3)) * (H * H) + off];
    else if (m == 5) v = Wr[((long)(l * 5 + 3)) * (H * H) + off];
    else if (m == 6) v = Wl[((long)(l * 5 + 4)) * (H * H) + off];
    else             v = Wr[((long)(l * 5 + 4)) * (H * H) + off];
    out[(long)job * 16384 + e] = f2b(v);
}

// ---------------- paper bias sums ----------------
__global__ void bsum_kernel(const float* __restrict__ bl, float* __restrict__ bsum_p) {
    int t = threadIdx.x;  // 256
    int l = t >> 7, i = t & 127;
    bsum_p[t] = bl[(long)(l * 5 + 0) * H + i] + bl[(long)(l * 5 + 1) * H + i] +
                bl[(long)(l * 5 + 2) * H + i];
}

// ---------------- combined CSR build ----------------
__device__ __forceinline__ void edge_map(long e, const int* w, const int* c, const int* p,
                                         const int* rw, const int* rp2, int half,
                                         int& val, int& bse) {
    if (e < 2 * EWC) {
        if (e < EWC) { val = w[e + (long)half * EWC]; bse = 0; }
        else { val = c[(e - EWC) + (long)half * EWC]; bse = NPC; }
    } else if (e < 2 * EWC + EPC) {
        val = p[(e - 2 * EWC) + (long)half * EPC]; bse = 2 * NPC;
    } else if (e < 3 * EWC + EPC) {
        val = rw[(e - 2 * EWC - EPC) + (long)half * EWC]; bse = 3 * NPC;
    } else {
        val = rp2[(e - 3 * EWC - EPC) + (long)half * EPC]; bse = 3 * NPC + NAC;
    }
}

__device__ __forceinline__ int ntl(const int* p) { return __builtin_nontemporal_load(p); }

__device__ __forceinline__ void edge_map_nt(long e, const int* w, const int* c, const int* p,
                                            const int* rw, const int* rp2, int half,
                                            int& val, int& bse) {
    if (e < 2 * EWC) {
        if (e < EWC) { val = ntl(w + e + (long)half * EWC); bse = 0; }
        else { val = ntl(c + (e - EWC) + (long)half * EWC); bse = NPC; }
    } else if (e < 2 * EWC + EPC) {
        val = ntl(p + (e - 2 * EWC) + (long)half * EPC); bse = 2 * NPC;
    } else if (e < 3 * EWC + EPC) {
        val = ntl(rw + (e - 2 * EWC - EPC) + (long)half * EWC); bse = 3 * NPC;
    } else {
        val = ntl(rp2 + (e - 3 * EWC - EPC) + (long)half * EPC); bse = 3 * NPC + NAC;
    }
}

__global__ void hist_all(const int* __restrict__ w, const int* __restrict__ c,
                         const int* __restrict__ p, const int* __restrict__ rw,
                         const int* __restrict__ rp2, int* __restrict__ deg) {
    long stride = (long)gridDim.x * blockDim.x;
    for (long e = (long)blockIdx.x * blockDim.x + threadIdx.x; e < ETOT; e += stride) {
        int d, b;
        edge_map(e, w, c, p, rw, rp2, 1, d, b);
        atomicAdd(&deg[b + d], 1);
    }
}

__global__ void scan_reduce(const int* __restrict__ deg, int* __restrict__ bsum, int n) {
    __shared__ int sdata[256];
    int b = blockIdx.x, t = threadIdx.x;
    int base = b * 1024;
    int s = 0;
#pragma unroll
    for (int j = 0; j < 4; ++j) {
        int i = base + t * 4 + j;
        if (i < n) s += deg[i];
    }
    sdata[t] = s;
    __syncthreads();
    for (int o = 128; o > 0; o >>= 1) {
        if (t < o) sdata[t] += sdata[t + o];
        __syncthreads();
    }
    if (t == 0) bsum[b] = sdata[0];
}

__global__ void scan_bsum(int* __restrict__ bsum, int nb) {
    if (threadIdx.x == 0 && blockIdx.x == 0) {
        int acc = 0;
        for (int i = 0; i < nb; ++i) {
            int v = bsum[i];
            bsum[i] = acc;
            acc += v;
        }
    }
}

// also zeroes deg (so fill can use it as cursor without an extra memset)
__global__ void scan_final(int* __restrict__ deg, const int* __restrict__ bsum,
                           int* __restrict__ row_ptr, int n, int E) {
    __shared__ int ssum[256];
    int b = blockIdx.x, t = threadIdx.x;
    int base = b * 1024;
    int v[4];
    int s = 0;
#pragma unroll
    for (int j = 0; j < 4; ++j) {
        int i = base + t * 4 + j;
        v[j] = (i < n) ? deg[i] : 0;
        if (i < n) deg[i] = 0;
        s += v[j];
    }
    ssum[t] = s;
    __syncthreads();
    for (int o = 1; o < 256; o <<= 1) {
        int x = (t >= o) ? ssum[t - o] : 0;
        __syncthreads();
        ssum[t] += x;
        __syncthreads();
    }
    int excl = bsum[b] + ((t > 0) ? ssum[t - 1] : 0);
#pragma unroll
    for (int j = 0; j < 4; ++j) {
        int i = base + t * 4 + j;
        if (i < n) {
            row_ptr[i] = excl;
            excl += v[j];
        }
    }
    if (b == 0 && t == 0) row_ptr[n] = E;
}

// ---------------- per-XCD partitioned fill ----------------
// Each block serves the work queue of its own XCD (node range = XCD id * XRANGE),
// so srcs_all writes land in a ~3.2 MB window resident in that XCD's private L2.
// Edge-stream reads are nontemporal to avoid evicting the write window.
// Work-stealing over all 8 queues guarantees completion for any block->XCD mapping.
__global__ __launch_bounds__(256) void fill_xcd(
    const int* __restrict__ w, const int* __restrict__ c, const int* __restrict__ p,
    const int* __restrict__ rw, const int* __restrict__ rp2,
    const int* __restrict__ gscan, int* __restrict__ cursor,
    int* __restrict__ srcs_all, int* __restrict__ qnext) {
    __shared__ int sc;
    int xcd;
    asm("s_getreg_b32 %0, hwreg(HW_REG_XCC_ID)" : "=s"(xcd));
    xcd &= 7;
    int t = threadIdx.x;
    for (int qi = 0; qi < 8; ++qi) {
        int q = (xcd + qi) & 7;
        int glo = q * XRANGE;
        int ghi = glo + XRANGE;
        if (ghi > NDEG) ghi = NDEG;
        for (;;) {
            __syncthreads();
            if (t == 0) sc = atomicAdd(&qnext[q * 16], 1);
            __syncthreads();
            int chunk = sc;
            if (chunk >= NCHUNK) break;
            long e0 = (long)chunk * CHUNKE;
            long e1 = e0 + CHUNKE;
            if (e1 > ETOT) e1 = ETOT;
            for (long e = e0 + t; e < e1; e += 256) {
                int d, b;
                edge_map_nt(e, w, c, p, rw, rp2, 1, d, b);
                int g = b + d;
                if (g >= glo && g < ghi) {
                    int s, b2;
                    edge_map_nt(e, w, c, p, rw, rp2, 0, s, b2);
                    int pos = atomicAdd(&cursor[g], 1);
                    srcs_all[gscan[g] + pos] = s;
                }
            }
        }
    }
}

// ---------------- zgemm4: 4-job batched MFMA GEMM, Z = A @ W -> bf16 ----------------
__global__ __launch_bounds__(256) void zgemm4(
    const u16* __restrict__ a0, const u16* __restrict__ w0, u16* __restrict__ o0, int t0,
    const u16* __restrict__ a1, const u16* __restrict__ w1, u16* __restrict__ o1, int t1,
    const u16* __restrict__ a2, const u16* __restrict__ w2, u16* __restrict__ o2, int t2,
    const u16* __restrict__ a3, const u16* __restrict__ w3, u16* __restrict__ o3) {
    int b = blockIdx.x;
    const u16 *A, *W;
    u16* O;
    int lb;
    if (b < t0)                { A = a0; W = w0; O = o0; lb = b; }
    else if (b < t0 + t1)      { A = a1; W = w1; O = o1; lb = b - t0; }
    else if (b < t0 + t1 + t2) { A = a2; W = w2; O = o2; lb = b - t0 - t1; }
    else                       { A = a3; W = w3; O = o3; lb = b - t0 - t1 - t2; }

    const int t = threadIdx.x;
    const int lane = t & 63;
    const int w = t >> 6;
    const int wr = w >> 1, wc = w & 1;
    const long base = (long)lb * 128;
    const int hi = (lane >> 4) & 3;
    const int lo = lane & 15;

    f32x4 acc[4][4];
#pragma unroll
    for (int i = 0; i < 4; ++i)
#pragma unroll
        for (int j = 0; j < 4; ++j) acc[i][j] = (f32x4){0.f, 0.f, 0.f, 0.f};

#pragma unroll
    for (int ks = 0; ks < 4; ++ks) {
        bf16x8 a[4];
#pragma unroll
        for (int fr = 0; fr < 4; ++fr) {
            long r = base + wr * 64 + fr * 16 + lo;
            a[fr] = *reinterpret_cast<const bf16x8*>(A + r * H + ks * 32 + hi * 8);
        }
#pragma unroll
        for (int fc = 0; fc < 4; ++fc) {
            int nb = wc * 4 + fc;
            bf16x8 bb = *reinterpret_cast<const bf16x8*>(W + ((ks * 8 + nb) * 512 + lane * 8));
#pragma unroll
            for (int fr = 0; fr < 4; ++fr)
                acc[fr][fc] = __builtin_amdgcn_mfma_f32_16x16x32_bf16(a[fr], bb, acc[fr][fc], 0, 0, 0);
        }
    }

#pragma unroll
    for (int fc = 0; fc < 4; ++fc) {
        int col = wc * 64 + fc * 16 + lo;
#pragma unroll
        for (int fr = 0; fr < 4; ++fr) {
#pragma unroll
            for (int i = 0; i < 4; ++i) {
                long g = base + wr * 64 + fr * 16 + hi * 4 + i;
                O[g * H + col] = f2b(acc[fr][fc][i]);
            }
        }
    }
}

// ---------------- final gather core ----------------
__device__ __forceinline__ void acc_mean(const u16* __restrict__ z,
                                         const int* __restrict__ ss,
                                         int beg, int end, int lane, int q, int l16,
                                         float ax[8]) {
    float t[8];
#pragma unroll
    for (int i = 0; i < 8; ++i) t[i] = 0.f;
    for (int c = beg; c < end; c += 64) {
        int m = end - c;
        if (m > 64) m = 64;
        int idx = (lane < m) ? ss[c + lane] : 0;
        for (int jj = 0; jj < m; jj += 4) {
            int s = __shfl(idx, jj + q, 64);
            if (jj + q < m) {
                const uint4 v = *reinterpret_cast<const uint4*>(z + (long)s * H + l16 * 8);
                t[0] += b2f((u16)(v.x & 0xffff)); t[1] += b2f((u16)(v.x >> 16));
                t[2] += b2f((u16)(v.y & 0xffff)); t[3] += b2f((u16)(v.y >> 16));
                t[4] += b2f((u16)(v.z & 0xffff)); t[5] += b2f((u16)(v.z >> 16));
                t[6] += b2f((u16)(v.w & 0xffff)); t[7] += b2f((u16)(v.w >> 16));
            }
        }
    }
    float inv = 1.0f / fmaxf((float)(end - beg), 1.0f);
#pragma unroll
    for (int i = 0; i < 8; ++i) ax[i] += t[i] * inv;
}

__device__ __forceinline__ void final_write(float ax[8], const u16* zself, long w,
                                            const float* __restrict__ bias, float scale,
                                            float* yf, u16* yb, int lane, int q, int l16) {
#pragma unroll
    for (int i = 0; i < 8; ++i) {
        ax[i] += __shfl_xor(ax[i], 32, 64);
        ax[i] += __shfl_xor(ax[i], 16, 64);
    }
    if (q == 0) {
        const uint4 sv = *reinterpret_cast<const uint4*>(zself + w * H + l16 * 8);
        float se[8] = {b2f((u16)(sv.x & 0xffff)), b2f((u16)(sv.x >> 16)),
                       b2f((u16)(sv.y & 0xffff)), b2f((u16)(sv.y >> 16)),
                       b2f((u16)(sv.z & 0xffff)), b2f((u16)(sv.z >> 16)),
                       b2f((u16)(sv.w & 0xffff)), b2f((u16)(sv.w >> 16))};
        const float4 b0 = *reinterpret_cast<const float4*>(bias + l16 * 8);
        const float4 b1 = *reinterpret_cast<const float4*>(bias + l16 * 8 + 4);
        float bb[8] = {b0.x, b0.y, b0.z, b0.w, b1.x, b1.y, b1.z, b1.w};
        float o[8];
#pragma unroll
        for (int i = 0; i < 8; ++i) o[i] = fmaxf((ax[i] + se[i] + bb[i]) * scale, 0.f);
        if (yf) {
            float* yp = yf + w * H + l16 * 8;
            *reinterpret_cast<float4*>(yp) = make_float4(o[0], o[1], o[2], o[3]);
            *reinterpret_cast<float4*>(yp + 4) = make_float4(o[4], o[5], o[6], o[7]);
        } else {
            uint4 ov;
            ov.x = (unsigned)f2b(o[0]) | ((unsigned)f2b(o[1]) << 16);
            ov.y = (unsigned)f2b(o[2]) | ((unsigned)f2b(o[3]) << 16);
            ov.z = (unsigned)f2b(o[4]) | ((unsigned)f2b(o[5]) << 16);
            ov.w = (unsigned)f2b(o[6]) | ((unsigned)f2b(o[7]) << 16);
            *reinterpret_cast<uint4*>(yb + w * H + l16 * 8) = ov;
        }
    }
}

// paper: 3 relations + self, scale 1/3
__global__ void final_paper(const u16* __restrict__ z0, const u16* __restrict__ z1,
                            const u16* __restrict__ z2, const u16* __restrict__ zps,
                            const int* __restrict__ gs, const int* __restrict__ ss,
                            const float* __restrict__ bias,
                            float* yf, u16* yb) {
    long gid = (long)blockIdx.x * blockDim.x + threadIdx.x;
    long w = gid >> 6;
    if (w >= NPC) return;
    int lane = (int)(gid & 63), q = lane >> 4, l16 = lane & 15;
    float ax[8] = {0.f, 0.f, 0.f, 0.f, 0.f, 0.f, 0.f, 0.f};
    acc_mean(z0, ss, gs[w], gs[w + 1], lane, q, l16, ax);
    acc_mean(z1, ss, gs[NPC + w], gs[NPC + w + 1], lane, q, l16, ax);
    acc_mean(z2, ss, gs[2 * NPC + w], gs[2 * NPC + w + 1], lane, q, l16, ax);
    final_write(ax, zps, w, bias, 1.0f / 3.0f, yf, yb, lane, q, l16);
}

// author + venue fused: 1 relation + self each, scale 1
__global__ void final_av(const u16* __restrict__ z3, const u16* __restrict__ zas,
                         const u16* __restrict__ z4, const u16* __restrict__ zvs,
                         const int* __restrict__ rp, const int* __restrict__ ss,
                         const float* __restrict__ bias3, const float* __restrict__ bias4,
                         float* yfa, u16* yba, float* yfv, u16* ybv) {
    long gid = (long)blockIdx.x * blockDim.x + threadIdx.x;
    long w = gid >> 6;
    if (w >= NAC + NVC) return;
    int lane = (int)(gid & 63), q = lane >> 4, l16 = lane & 15;
    float ax[8] = {0.f, 0.f, 0.f, 0.f, 0.f, 0.f, 0.f, 0.f};
    if (w < NAC) {
        acc_mean(z3, ss, rp[w], rp[w + 1], lane, q, l16, ax);
        final_write(ax, zas, w, bias3, 1.0f, yfa, yba, lane, q, l16);
    } else {
        long wv = w - NAC;
        acc_mean(z4, ss, rp[NAC + wv], rp[NAC + wv + 1], lane, q, l16, ax);
        final_write(ax, zvs, wv, bias4, 1.0f, yfv, ybv, lane, q, l16);
    }
}

extern "C" void kernel_launch(void* const* d_in, const int* in_sizes, int n_in,
                              void* d_out, int out_size, void* d_ws, size_t ws_size,
                              hipStream_t stream) {
    const float* xp0 = (const float*)d_in[0];
    const float* xa0 = (const float*)d_in[1];
    const float* xv0 = (const float*)d_in[2];
    const float* Wl  = (const float*)d_in[3];
    const float* bl  = (const float*)d_in[4];
    const float* Wr  = (const float*)d_in[5];
    const int* ei_w  = (const int*)d_in[6];
    const int* ei_c  = (const int*)d_in[7];
    const int* ei_p  = (const int*)d_in[8];
    const int* ei_rw = (const int*)d_in[9];
    const int* ei_rp = (const int*)d_in[10];

    char* cur = (char*)d_ws;
    auto alloc = [&](long bytes) { char* r = cur; cur += (bytes + 255) & ~255L; return r; };
    u16* xpb   = (u16*)alloc((long)NPP * H * 2);
    u16* xab   = (u16*)alloc((long)NAP * H * 2);
    u16* xvb   = (u16*)alloc((long)NVP * H * 2);
    u16* packw = (u16*)alloc(16 * 16384 * 2);
    float* bsum_p = (float*)alloc(256 * 4);
    int* gscan    = (int*)alloc((NDEG + 1) * 4);
    int* deg      = (int*)alloc(NDEG * 4);
    int* srcs_all = (int*)alloc((long)ETOT * 4);
    int* bsums    = (int*)alloc(((NDEG + 1023) / 1024) * 4);
    int* qnext    = (int*)alloc(8 * 16 * 4);
    u16* Z        = (u16*)alloc((long)(2 * NPP + NAP + NVP) * H * 2);  // 130.6 MB phase region

    // Z job pointers (shared across phases)
    u16* zj0 = Z;                                   // NPP rows (zps / z3)
    u16* zj1 = Z + (long)NPP * H;                   // NAP rows (z0 / zas)
    u16* zj2 = Z + (long)(NPP + NAP) * H;           // NPP rows (z1 / z4)
    u16* zj3 = Z + (long)(2 * NPP + NAP) * H;       // NVP rows (z2 / zvs)

    // layer-0 output stage in d_out (bf16), overwritten last by layer-1 paper final
    u16* sp = (u16*)d_out;
    u16* sa = sp + (long)NPP * H;
    u16* sv = sa + (long)NAP * H;

    float* op = (float*)d_out;
    float* oa = op + (long)NPC * H;
    float* ov = oa + (long)NAC * H;

    // ---- prep ----
    cast_kernel<<<2048, 256, 0, stream>>>(xp0, xpb, (long)NPC * H / 4);
    cast_kernel<<<1024, 256, 0, stream>>>(xa0, xab, (long)NAC * H / 4);
    cast_kernel<<<256, 256, 0, stream>>>(xv0, xvb, (long)NVC * H / 4);
    pack_kernel<<<1024, 256, 0, stream>>>(Wl, Wr, packw);
    bsum_kernel<<<1, 256, 0, stream>>>(bl, bsum_p);

    // ---- CSR build ----
    hipMemsetAsync(deg, 0, NDEG * 4, stream);
    hipMemsetAsync(qnext, 0, 8 * 16 * 4, stream);
    hist_all<<<2048, 256, 0, stream>>>(ei_w, ei_c, ei_p, ei_rw, ei_rp, deg);
    int nb = (NDEG + 1023) / 1024;
    scan_reduce<<<nb, 256, 0, stream>>>(deg, bsums, NDEG);
    scan_bsum<<<1, 64, 0, stream>>>(bsums, nb);
    scan_final<<<nb, 256, 0, stream>>>(deg, bsums, gscan, NDEG, ETOT);  // also zeroes deg
    fill_xcd<<<2048, 256, 0, stream>>>(ei_w, ei_c, ei_p, ei_rw, ei_rp, gscan, deg,
                                       srcs_all, qnext);

    auto PW = [&](int l, int m) { return packw + (long)(l * 8 + m) * 16384; };
    const int NT = TP + TA + TP + TV;  // 3987
    auto GVB = [&](long n) { return (int)((n * 64 + 255) / 256); };

    auto run_layer = [&](int l, const u16* xp, const u16* xa, const u16* xv,
                         float* yfp, u16* ybp, float* yfa, u16* yba,
                         float* yfv, u16* ybv) {
        // phase BC: z3 = xp@Wl3, zas = xa@Wr3, z4 = xp@Wl4, zvs = xv@Wr4
        zgemm4<<<NT, 256, 0, stream>>>(xp, PW(l, 4), zj0, TP,
                                       xa, PW(l, 5), zj1, TA,
                                       xp, PW(l, 6), zj2, TP,
                                       xv, PW(l, 7), zj3);
        final_av<<<GVB(NAC + NVC), 256, 0, stream>>>(
            zj0, zj1, zj2, zj3, gscan + 3 * NPC, srcs_all,
            bl + (long)(l * 5 + 3) * H, bl + (long)(l * 5 + 4) * H,
            yfa, yba, yfv, ybv);
        // phase A: zps = xp@sumWr, z0 = xa@Wl0, z1 = xp@Wl1, z2 = xv@Wl2
        zgemm4<<<NT, 256, 0, stream>>>(xp, PW(l, 3), zj0, TP,
                                       xa, PW(l, 0), zj1, TA,
                                       xp, PW(l, 1), zj2, TP,
                                       xv, PW(l, 2), zj3);
        final_paper<<<GVB(NPC), 256, 0, stream>>>(
            zj1, zj2, zj3, zj0, gscan, srcs_all, bsum_p + l * 128, yfp, ybp);
    };

    // layer 0: bf16 outputs staged in d_out
    run_layer(0, xpb, xab, xvb, nullptr, sp, nullptr, sa, nullptr, sv);
    // layer 1: f32 outputs into d_out (paper final last, overwrites stage after all reads)
    run_layer(1, sp, sa, sv, op, nullptr, oa, nullptr, ov, nullptr);
}

// Round 12
// 1165.197 us; speedup vs baseline: 1.3890x; 1.3890x over previous
//
#include <hip/hip_runtime.h>

#define H 128
typedef unsigned short u16;
typedef unsigned long long u64;
typedef __attribute__((ext_vector_type(8))) short bf16x8;
typedef __attribute__((ext_vector_type(4))) float f32x4;

#define NPC 200000
#define NAC 100000
#define NVC 10000
#define EWC 2000000
#define EPC 200000
#define ETOT 6400000
#define NDEG 710000
#define NPP 200064
#define NAP 100096
#define NVP 10112
#define TP 1563
#define TA 782
#define TV 79
#define CBW2 2774     // nodes per coarse bucket (256*2774 = 710144 >= NDEG)
#define NB1 2048      // pass1 blocks
#define EPB1 3125     // edges per pass1 block (2048*3125 == ETOT)
#define NSC (256 * NB1)

__device__ __forceinline__ u16 f2b(float f) {
    unsigned u = __builtin_bit_cast(unsigned, f);
    unsigned r = (u + 0x7fff + ((u >> 16) & 1)) >> 16;
    return (u16)r;
}
__device__ __forceinline__ float b2f(u16 b) {
    unsigned u = ((unsigned)b) << 16;
    return __builtin_bit_cast(float, u);
}

// ---------------- cast f32 -> bf16 ----------------
__global__ void cast_kernel(const float* __restrict__ in, u16* __restrict__ out, long n4) {
    long stride = (long)gridDim.x * blockDim.x;
    for (long i = (long)blockIdx.x * blockDim.x + threadIdx.x; i < n4; i += stride) {
        float4 v = reinterpret_cast<const float4*>(in)[i];
        ushort4 o;
        o.x = f2b(v.x); o.y = f2b(v.y); o.z = f2b(v.z); o.w = f2b(v.w);
        reinterpret_cast<ushort4*>(out)[i] = o;
    }
}

// ---------------- pack weights into MFMA B-fragment layout (bf16) ----------------
// jobs m: 0-2: Wl[l,m]; 3: sum Wr[l,0..2]; 4: Wl[l,3]; 5: Wr[l,3]; 6: Wl[l,4]; 7: Wr[l,4]
__global__ void pack_kernel(const float* __restrict__ Wl, const float* __restrict__ Wr,
                            u16* __restrict__ out) {
    int tid = blockIdx.x * blockDim.x + threadIdx.x;  // 16*16384
    int e = tid & 16383;
    int job = tid >> 14;
    int l = job >> 3, m = job & 7;
    int lane = (e >> 3) & 63;
    int j = e & 7;
    int knb = e >> 9;  // 0..31
    int k = (knb >> 3) * 32 + ((lane >> 4) & 3) * 8 + j;
    int n = (knb & 7) * 16 + (lane & 15);
    long off = (long)k * H + n;
    float v;
    if (m < 3) v = Wl[((long)(l * 5 + m)) * (H * H) + off];
    else if (m == 3) v = Wr[((long)(l * 5 + 0)) * (H * H) + off] +
                         Wr[((long)(l * 5 + 1)) * (H * H) + off] +
                         Wr[((long)(l * 5 + 2)) * (H * H) + off];
    else if (m == 4) v = Wl[((long)(l * 5 + 3)) * (H * H) + off];
    else if (m == 5) v = Wr[((long)(l * 5 + 3)) * (H * H) + off];
    else if (m == 6) v = Wl[((long)(l * 5 + 4)) * (H * H) + off];
    else             v = Wr[((long)(l * 5 + 4)) * (H * H) + off];
    out[(long)job * 16384 + e] = f2b(v);
}

// ---------------- paper bias sums ----------------
__global__ void bsum_kernel(const float* __restrict__ bl, float* __restrict__ bsum_p) {
    int t = threadIdx.x;  // 256
    int l = t >> 7, i = t & 127;
    bsum_p[t] = bl[(long)(l * 5 + 0) * H + i] + bl[(long)(l * 5 + 1) * H + i] +
                bl[(long)(l * 5 + 2) * H + i];
}

// ---------------- edge decode over 5 concatenated relations ----------------
__device__ __forceinline__ void edge_map(long e, const int* w, const int* c, const int* p,
                                         const int* rw, const int* rp2, int half,
                                         int& val, int& bse) {
    if (e < 2 * EWC) {
        if (e < EWC) { val = w[e + (long)half * EWC]; bse = 0; }
        else { val = c[(e - EWC) + (long)half * EWC]; bse = NPC; }
    } else if (e < 2 * EWC + EPC) {
        val = p[(e - 2 * EWC) + (long)half * EPC]; bse = 2 * NPC;
    } else if (e < 3 * EWC + EPC) {
        val = rw[(e - 2 * EWC - EPC) + (long)half * EWC]; bse = 3 * NPC;
    } else {
        val = rp2[(e - 3 * EWC - EPC) + (long)half * EPC]; bse = 3 * NPC + NAC;
    }
}

// ---------------- generic scan machinery (1024 elems / block) ----------------
__global__ void scan_reduce(const int* __restrict__ deg, int* __restrict__ bsum, int n) {
    __shared__ int sdata[256];
    int b = blockIdx.x, t = threadIdx.x;
    int base = b * 1024;
    int s = 0;
#pragma unroll
    for (int j = 0; j < 4; ++j) {
        int i = base + t * 4 + j;
        if (i < n) s += deg[i];
    }
    sdata[t] = s;
    __syncthreads();
    for (int o = 128; o > 0; o >>= 1) {
        if (t < o) sdata[t] += sdata[t + o];
        __syncthreads();
    }
    if (t == 0) bsum[b] = sdata[0];
}

__global__ void scan_bsum(int* __restrict__ bsum, int nb) {
    if (threadIdx.x == 0 && blockIdx.x == 0) {
        int acc = 0;
        for (int i = 0; i < nb; ++i) {
            int v = bsum[i];
            bsum[i] = acc;
            acc += v;
        }
    }
}

__global__ void scan_final(const int* __restrict__ deg, const int* __restrict__ bsum,
                           int* __restrict__ row_ptr, int n, int E) {
    __shared__ int ssum[256];
    int b = blockIdx.x, t = threadIdx.x;
    int base = b * 1024;
    int v[4];
    int s = 0;
#pragma unroll
    for (int j = 0; j < 4; ++j) {
        int i = base + t * 4 + j;
        v[j] = (i < n) ? deg[i] : 0;
        s += v[j];
    }
    ssum[t] = s;
    __syncthreads();
    for (int o = 1; o < 256; o <<= 1) {
        int x = (t >= o) ? ssum[t - o] : 0;
        __syncthreads();
        ssum[t] += x;
        __syncthreads();
    }
    int excl = bsum[b] + ((t > 0) ? ssum[t - 1] : 0);
#pragma unroll
    for (int j = 0; j < 4; ++j) {
        int i = base + t * 4 + j;
        if (i < n) {
            row_ptr[i] = excl;
            excl += v[j];
        }
    }
    if (b == 0 && t == 0) row_ptr[n] = E;
}

// ---------------- pass1a: per-block 256-bucket histogram ----------------
__global__ __launch_bounds__(256) void hist1(const int* __restrict__ w, const int* __restrict__ c,
                                             const int* __restrict__ p, const int* __restrict__ rw,
                                             const int* __restrict__ rp2, int* __restrict__ bh) {
    __shared__ int lh[256];
    int t = threadIdx.x, blk = blockIdx.x;
    lh[t] = 0;
    __syncthreads();
    long e0 = (long)blk * EPB1;
    for (int i = t; i < EPB1; i += 256) {
        int d, b;
        edge_map(e0 + i, w, c, p, rw, rp2, 1, d, b);
        atomicAdd(&lh[(b + d) / CBW2], 1);
    }
    __syncthreads();
    bh[t * NB1 + blk] = lh[t];  // bucket-major for the scan
}

// ---------------- pass1b: LDS-sort chunk by bucket, write runs contiguously ----------------
__global__ __launch_bounds__(256) void scatter1(const int* __restrict__ w, const int* __restrict__ c,
                                                const int* __restrict__ p, const int* __restrict__ rw,
                                                const int* __restrict__ rp2,
                                                const int* __restrict__ bhscan,
                                                u64* __restrict__ binned) {
    __shared__ u64 sorted[EPB1];
    __shared__ int lh[256];     // hist then cursor
    __shared__ int lofs[256];   // local exclusive offsets
    __shared__ int gbase[256];
    int t = threadIdx.x, blk = blockIdx.x;
    lh[t] = 0;
    gbase[t] = bhscan[t * NB1 + blk];
    __syncthreads();
    long e0 = (long)blk * EPB1;
    for (int i = t; i < EPB1; i += 256) {
        int d, b;
        edge_map(e0 + i, w, c, p, rw, rp2, 1, d, b);
        atomicAdd(&lh[(b + d) / CBW2], 1);
    }
    __syncthreads();
    int own = lh[t];
    lofs[t] = own;
    __syncthreads();
    for (int o = 1; o < 256; o <<= 1) {
        int v = (t >= o) ? lofs[t - o] : 0;
        __syncthreads();
        lofs[t] += v;
        __syncthreads();
    }
    int excl = lofs[t] - own;
    __syncthreads();
    lofs[t] = excl;
    lh[t] = excl;  // cursor
    __syncthreads();
    for (int i = t; i < EPB1; i += 256) {
        int d, b, s, b2;
        edge_map(e0 + i, w, c, p, rw, rp2, 1, d, b);
        edge_map(e0 + i, w, c, p, rw, rp2, 0, s, b2);
        int g = b + d;
        int pos = atomicAdd(&lh[g / CBW2], 1);
        sorted[pos] = ((u64)(unsigned)g << 32) | (unsigned)s;
    }
    __syncthreads();
    for (int i = t; i < EPB1; i += 256) {
        u64 ent = sorted[i];
        int g = (int)(ent >> 32);
        int bk = g / CBW2;
        binned[(long)gbase[bk] + (i - lofs[bk])] = ent;
    }
}

// ---------------- pass2: per-bucket LDS hist+scan -> gscan, place srcs ----------------
__global__ __launch_bounds__(256) void pass2(const u64* __restrict__ binned,
                                             const int* __restrict__ bhscan,
                                             int* __restrict__ gscan,
                                             int* __restrict__ srcs_all) {
    __shared__ int cnt[CBW2];
    __shared__ int exc[CBW2];
    __shared__ int psum[256];
    int cb = blockIdx.x, t = threadIdx.x;
    int n0 = cb * CBW2;
    int n1 = n0 + CBW2;
    if (n1 > NDEG) n1 = NDEG;
    int nn = n1 - n0;
    for (int i = t; i < nn; i += 256) cnt[i] = 0;
    __syncthreads();
    int e0 = bhscan[cb * NB1];
    int e1 = (cb == 255) ? ETOT : bhscan[(cb + 1) * NB1];
    for (int e = e0 + t; e < e1; e += 256) {
        int g = (int)(binned[e] >> 32);
        atomicAdd(&cnt[g - n0], 1);
    }
    __syncthreads();
    int o0 = t * 11;  // 256*11 = 2816 >= 2774
    int s = 0;
#pragma unroll
    for (int k = 0; k < 11; ++k) {
        int i = o0 + k;
        int v = (i < nn) ? cnt[i] : 0;
        if (i < CBW2) exc[i] = s;
        s += v;
    }
    psum[t] = s;
    __syncthreads();
    for (int o = 1; o < 256; o <<= 1) {
        int v = (t >= o) ? psum[t - o] : 0;
        __syncthreads();
        psum[t] += v;
        __syncthreads();
    }
    int eoff = psum[t] - s;
#pragma unroll
    for (int k = 0; k < 11; ++k) {
        int i = o0 + k;
        if (i < CBW2) exc[i] += eoff;
    }
    __syncthreads();
    for (int i = t; i < nn; i += 256) {
        gscan[n0 + i] = e0 + exc[i];
        cnt[i] = 0;
    }
    if (cb == 255 && t == 0) gscan[NDEG] = ETOT;
    __syncthreads();
    for (int e = e0 + t; e < e1; e += 256) {
        u64 v = binned[e];
        int g = (int)(v >> 32);
        int s2 = (int)(v & 0xffffffffu);
        int loc = g - n0;
        int pos = atomicAdd(&cnt[loc], 1);
        srcs_all[e0 + exc[loc] + pos] = s2;
    }
}

// ---------------- zgemm4: 4-job batched MFMA GEMM, Z = A @ W -> bf16 ----------------
__global__ __launch_bounds__(256) void zgemm4(
    const u16* __restrict__ a0, const u16* __restrict__ w0, u16* __restrict__ o0, int t0,
    const u16* __restrict__ a1, const u16* __restrict__ w1, u16* __restrict__ o1, int t1,
    const u16* __restrict__ a2, const u16* __restrict__ w2, u16* __restrict__ o2, int t2,
    const u16* __restrict__ a3, const u16* __restrict__ w3, u16* __restrict__ o3) {
    int b = blockIdx.x;
    const u16 *A, *W;
    u16* O;
    int lb;
    if (b < t0)                { A = a0; W = w0; O = o0; lb = b; }
    else if (b < t0 + t1)      { A = a1; W = w1; O = o1; lb = b - t0; }
    else if (b < t0 + t1 + t2) { A = a2; W = w2; O = o2; lb = b - t0 - t1; }
    else                       { A = a3; W = w3; O = o3; lb = b - t0 - t1 - t2; }

    const int t = threadIdx.x;
    const int lane = t & 63;
    const int w = t >> 6;
    const int wr = w >> 1, wc = w & 1;
    const long base = (long)lb * 128;
    const int hi = (lane >> 4) & 3;
    const int lo = lane & 15;

    f32x4 acc[4][4];
#pragma unroll
    for (int i = 0; i < 4; ++i)
#pragma unroll
        for (int j = 0; j < 4; ++j) acc[i][j] = (f32x4){0.f, 0.f, 0.f, 0.f};

#pragma unroll
    for (int ks = 0; ks < 4; ++ks) {
        bf16x8 a[4];
#pragma unroll
        for (int fr = 0; fr < 4; ++fr) {
            long r = base + wr * 64 + fr * 16 + lo;
            a[fr] = *reinterpret_cast<const bf16x8*>(A + r * H + ks * 32 + hi * 8);
        }
#pragma unroll
        for (int fc = 0; fc < 4; ++fc) {
            int nb = wc * 4 + fc;
            bf16x8 bb = *reinterpret_cast<const bf16x8*>(W + ((ks * 8 + nb) * 512 + lane * 8));
#pragma unroll
            for (int fr = 0; fr < 4; ++fr)
                acc[fr][fc] = __builtin_amdgcn_mfma_f32_16x16x32_bf16(a[fr], bb, acc[fr][fc], 0, 0, 0);
        }
    }

#pragma unroll
    for (int fc = 0; fc < 4; ++fc) {
        int col = wc * 64 + fc * 16 + lo;
#pragma unroll
        for (int fr = 0; fr < 4; ++fr) {
#pragma unroll
            for (int i = 0; i < 4; ++i) {
                long g = base + wr * 64 + fr * 16 + hi * 4 + i;
                O[g * H + col] = f2b(acc[fr][fc][i]);
            }
        }
    }
}

// ---------------- final gather core ----------------
__device__ __forceinline__ void acc_mean(const u16* __restrict__ z,
                                         const int* __restrict__ ss,
                                         int beg, int end, int lane, int q, int l16,
                                         float ax[8]) {
    float t[8];
#pragma unroll
    for (int i = 0; i < 8; ++i) t[i] = 0.f;
    for (int c = beg; c < end; c += 64) {
        int m = end - c;
        if (m > 64) m = 64;
        int idx = (lane < m) ? ss[c + lane] : 0;
        for (int jj = 0; jj < m; jj += 4) {
            int s = __shfl(idx, jj + q, 64);
            if (jj + q < m) {
                const uint4 v = *reinterpret_cast<const uint4*>(z + (long)s * H + l16 * 8);
                t[0] += b2f((u16)(v.x & 0xffff)); t[1] += b2f((u16)(v.x >> 16));
                t[2] += b2f((u16)(v.y & 0xffff)); t[3] += b2f((u16)(v.y >> 16));
                t[4] += b2f((u16)(v.z & 0xffff)); t[5] += b2f((u16)(v.z >> 16));
                t[6] += b2f((u16)(v.w & 0xffff)); t[7] += b2f((u16)(v.w >> 16));
            }
        }
    }
    float inv = 1.0f / fmaxf((float)(end - beg), 1.0f);
#pragma unroll
    for (int i = 0; i < 8; ++i) ax[i] += t[i] * inv;
}

__device__ __forceinline__ void final_write(float ax[8], const u16* zself, long w,
                                            const float* __restrict__ bias, float scale,
                                            float* yf, u16* yb, int lane, int q, int l16) {
#pragma unroll
    for (int i = 0; i < 8; ++i) {
        ax[i] += __shfl_xor(ax[i], 32, 64);
        ax[i] += __shfl_xor(ax[i], 16, 64);
    }
    if (q == 0) {
        const uint4 sv = *reinterpret_cast<const uint4*>(zself + w * H + l16 * 8);
        float se[8] = {b2f((u16)(sv.x & 0xffff)), b2f((u16)(sv.x >> 16)),
                       b2f((u16)(sv.y & 0xffff)), b2f((u16)(sv.y >> 16)),
                       b2f((u16)(sv.z & 0xffff)), b2f((u16)(sv.z >> 16)),
                       b2f((u16)(sv.w & 0xffff)), b2f((u16)(sv.w >> 16))};
        const float4 b0 = *reinterpret_cast<const float4*>(bias + l16 * 8);
        const float4 b1 = *reinterpret_cast<const float4*>(bias + l16 * 8 + 4);
        float bb[8] = {b0.x, b0.y, b0.z, b0.w, b1.x, b1.y, b1.z, b1.w};
        float o[8];
#pragma unroll
        for (int i = 0; i < 8; ++i) o[i] = fmaxf((ax[i] + se[i] + bb[i]) * scale, 0.f);
        if (yf) {
            float* yp = yf + w * H + l16 * 8;
            *reinterpret_cast<float4*>(yp) = make_float4(o[0], o[1], o[2], o[3]);
            *reinterpret_cast<float4*>(yp + 4) = make_float4(o[4], o[5], o[6], o[7]);
        } else {
            uint4 ov;
            ov.x = (unsigned)f2b(o[0]) | ((unsigned)f2b(o[1]) << 16);
            ov.y = (unsigned)f2b(o[2]) | ((unsigned)f2b(o[3]) << 16);
            ov.z = (unsigned)f2b(o[4]) | ((unsigned)f2b(o[5]) << 16);
            ov.w = (unsigned)f2b(o[6]) | ((unsigned)f2b(o[7]) << 16);
            *reinterpret_cast<uint4*>(yb + w * H + l16 * 8) = ov;
        }
    }
}

// paper: 3 relations + self, scale 1/3
__global__ void final_paper(const u16* __restrict__ z0, const u16* __restrict__ z1,
                            const u16* __restrict__ z2, const u16* __restrict__ zps,
                            const int* __restrict__ gs, const int* __restrict__ ss,
                            const float* __restrict__ bias,
                            float* yf, u16* yb) {
    long gid = (long)blockIdx.x * blockDim.x + threadIdx.x;
    long w = gid >> 6;
    if (w >= NPC) return;
    int lane = (int)(gid & 63), q = lane >> 4, l16 = lane & 15;
    float ax[8] = {0.f, 0.f, 0.f, 0.f, 0.f, 0.f, 0.f, 0.f};
    acc_mean(z0, ss, gs[w], gs[w + 1], lane, q, l16, ax);
    acc_mean(z1, ss, gs[NPC + w], gs[NPC + w + 1], lane, q, l16, ax);
    acc_mean(z2, ss, gs[2 * NPC + w], gs[2 * NPC + w + 1], lane, q, l16, ax);
    final_write(ax, zps, w, bias, 1.0f / 3.0f, yf, yb, lane, q, l16);
}

// author + venue fused: 1 relation + self each, scale 1
__global__ void final_av(const u16* __restrict__ z3, const u16* __restrict__ zas,
                         const u16* __restrict__ z4, const u16* __restrict__ zvs,
                         const int* __restrict__ rp, const int* __restrict__ ss,
                         const float* __restrict__ bias3, const float* __restrict__ bias4,
                         float* yfa, u16* yba, float* yfv, u16* ybv) {
    long gid = (long)blockIdx.x * blockDim.x + threadIdx.x;
    long w = gid >> 6;
    if (w >= NAC + NVC) return;
    int lane = (int)(gid & 63), q = lane >> 4, l16 = lane & 15;
    float ax[8] = {0.f, 0.f, 0.f, 0.f, 0.f, 0.f, 0.f, 0.f};
    if (w < NAC) {
        acc_mean(z3, ss, rp[w], rp[w + 1], lane, q, l16, ax);
        final_write(ax, zas, w, bias3, 1.0f, yfa, yba, lane, q, l16);
    } else {
        long wv = w - NAC;
        acc_mean(z4, ss, rp[NAC + wv], rp[NAC + wv + 1], lane, q, l16, ax);
        final_write(ax, zvs, wv, bias4, 1.0f, yfv, ybv, lane, q, l16);
    }
}

extern "C" void kernel_launch(void* const* d_in, const int* in_sizes, int n_in,
                              void* d_out, int out_size, void* d_ws, size_t ws_size,
                              hipStream_t stream) {
    const float* xp0 = (const float*)d_in[0];
    const float* xa0 = (const float*)d_in[1];
    const float* xv0 = (const float*)d_in[2];
    const float* Wl  = (const float*)d_in[3];
    const float* bl  = (const float*)d_in[4];
    const float* Wr  = (const float*)d_in[5];
    const int* ei_w  = (const int*)d_in[6];
    const int* ei_c  = (const int*)d_in[7];
    const int* ei_p  = (const int*)d_in[8];
    const int* ei_rw = (const int*)d_in[9];
    const int* ei_rp = (const int*)d_in[10];

    char* cur = (char*)d_ws;
    auto alloc = [&](long bytes) { char* r = cur; cur += (bytes + 255) & ~255L; return r; };
    u16* xpb   = (u16*)alloc((long)NPP * H * 2);
    u16* xab   = (u16*)alloc((long)NAP * H * 2);
    u16* xvb   = (u16*)alloc((long)NVP * H * 2);
    u16* packw = (u16*)alloc(16 * 16384 * 2);
    float* bsum_p = (float*)alloc(256 * 4);
    int* gscan    = (int*)alloc((NDEG + 1) * 4);
    int* srcs_all = (int*)alloc((long)ETOT * 4);
    int* bh       = (int*)alloc((long)NSC * 4);        // 2 MB
    int* bhscan   = (int*)alloc((long)(NSC + 1) * 4);  // 2 MB
    int* bsums    = (int*)alloc(((NSC + 1023) / 1024) * 4);
    u16* Z        = (u16*)alloc((long)(2 * NPP + NAP + NVP) * H * 2);  // 130.6 MB

    // binned aliases Z (dead during CSR build): ETOT*8 = 51.2 MB << 130.6 MB
    u64* binned = (u64*)Z;

    // Z job pointers (shared across phases)
    u16* zj0 = Z;
    u16* zj1 = Z + (long)NPP * H;
    u16* zj2 = Z + (long)(NPP + NAP) * H;
    u16* zj3 = Z + (long)(2 * NPP + NAP) * H;

    // layer-0 output stage in d_out (bf16), overwritten last by layer-1 paper final
    u16* sp = (u16*)d_out;
    u16* sa = sp + (long)NPP * H;
    u16* sv = sa + (long)NAP * H;

    float* op = (float*)d_out;
    float* oa = op + (long)NPC * H;
    float* ov = oa + (long)NAC * H;

    // ---- prep ----
    cast_kernel<<<2048, 256, 0, stream>>>(xp0, xpb, (long)NPC * H / 4);
    cast_kernel<<<1024, 256, 0, stream>>>(xa0, xab, (long)NAC * H / 4);
    cast_kernel<<<256, 256, 0, stream>>>(xv0, xvb, (long)NVC * H / 4);
    pack_kernel<<<1024, 256, 0, stream>>>(Wl, Wr, packw);
    bsum_kernel<<<1, 256, 0, stream>>>(bl, bsum_p);

    // ---- CSR build: radix partition (no memsets, no global hist) ----
    hist1<<<NB1, 256, 0, stream>>>(ei_w, ei_c, ei_p, ei_rw, ei_rp, bh);
    int nb = (NSC + 1023) / 1024;  // 512
    scan_reduce<<<nb, 256, 0, stream>>>(bh, bsums, NSC);
    scan_bsum<<<1, 64, 0, stream>>>(bsums, nb);
    scan_final<<<nb, 256, 0, stream>>>(bh, bsums, bhscan, NSC, ETOT);
    scatter1<<<NB1, 256, 0, stream>>>(ei_w, ei_c, ei_p, ei_rw, ei_rp, bhscan, binned);
    pass2<<<256, 256, 0, stream>>>(binned, bhscan, gscan, srcs_all);

    auto PW = [&](int l, int m) { return packw + (long)(l * 8 + m) * 16384; };
    const int NT = TP + TA + TP + TV;  // 3987
    auto GVB = [&](long n) { return (int)((n * 64 + 255) / 256); };

    auto run_layer = [&](int l, const u16* xp, const u16* xa, const u16* xv,
                         float* yfp, u16* ybp, float* yfa, u16* yba,
                         float* yfv, u16* ybv) {
        // phase BC: z3 = xp@Wl3, zas = xa@Wr3, z4 = xp@Wl4, zvs = xv@Wr4
        zgemm4<<<NT, 256, 0, stream>>>(xp, PW(l, 4), zj0, TP,
                                       xa, PW(l, 5), zj1, TA,
                                       xp, PW(l, 6), zj2, TP,
                                       xv, PW(l, 7), zj3);
        final_av<<<GVB(NAC + NVC), 256, 0, stream>>>(
            zj0, zj1, zj2, zj3, gscan + 3 * NPC, srcs_all,
            bl + (long)(l * 5 + 3) * H, bl + (long)(l * 5 + 4) * H,
            yfa, yba, yfv, ybv);
        // phase A: zps = xp@sumWr, z0 = xa@Wl0, z1 = xp@Wl1, z2 = xv@Wl2
        zgemm4<<<NT, 256, 0, stream>>>(xp, PW(l, 3), zj0, TP,
                                       xa, PW(l, 0), zj1, TA,
                                       xp, PW(l, 1), zj2, TP,
                                       xv, PW(l, 2), zj3);
        final_paper<<<GVB(NPC), 256, 0, stream>>>(
            zj1, zj2, zj3, zj0, gscan, srcs_all, bsum_p + l * 128, yfp, ybp);
    };

    // layer 0: bf16 outputs staged in d_out
    run_layer(0, xpb, xab, xvb, nullptr, sp, nullptr, sa, nullptr, sv);
    // layer 1: f32 outputs into d_out (paper final last, overwrites stage after all reads)
    run_layer(1, sp, sa, sv, op, nullptr, oa, nullptr, ov, nullptr);
}

// Round 13
// 1085.230 us; speedup vs baseline: 1.4913x; 1.0737x over previous
//
#include <hip/hip_runtime.h>

#define H 128
typedef unsigned short u16;
typedef unsigned long long u64;
typedef __attribute__((ext_vector_type(8))) short bf16x8;
typedef __attribute__((ext_vector_type(4))) float f32x4;

#define NPC 200000
#define NAC 100000
#define NVC 10000
#define EWC 2000000
#define EPC 200000
#define ETOT 6400000
#define NDEG 710000
#define NPP 200064
#define NAP 100096
#define NVP 10112
#define TP 1563
#define TA 782
#define TV 79
#define CBW2 2774     // nodes per coarse bucket (256*2774 = 710144 >= NDEG)
#define NB1 2048      // pass1 blocks
#define EPB1 3125     // edges per pass1 block (2048*3125 == ETOT)
#define NSC (256 * NB1)

__device__ __forceinline__ u16 f2b(float f) {
    unsigned u = __builtin_bit_cast(unsigned, f);
    unsigned r = (u + 0x7fff + ((u >> 16) & 1)) >> 16;
    return (u16)r;
}
__device__ __forceinline__ float b2f(u16 b) {
    unsigned u = ((unsigned)b) << 16;
    return __builtin_bit_cast(float, u);
}

// ---------------- cast f32 -> bf16 ----------------
__global__ void cast_kernel(const float* __restrict__ in, u16* __restrict__ out, long n4) {
    long stride = (long)gridDim.x * blockDim.x;
    for (long i = (long)blockIdx.x * blockDim.x + threadIdx.x; i < n4; i += stride) {
        float4 v = reinterpret_cast<const float4*>(in)[i];
        ushort4 o;
        o.x = f2b(v.x); o.y = f2b(v.y); o.z = f2b(v.z); o.w = f2b(v.w);
        reinterpret_cast<ushort4*>(out)[i] = o;
    }
}

// ---------------- pack weights into MFMA B-fragment layout (bf16) ----------------
// jobs m: 0-2: Wl[l,m]; 3: sum Wr[l,0..2]; 4: Wl[l,3]; 5: Wr[l,3]; 6: Wl[l,4]; 7: Wr[l,4]
__global__ void pack_kernel(const float* __restrict__ Wl, const float* __restrict__ Wr,
                            u16* __restrict__ out) {
    int tid = blockIdx.x * blockDim.x + threadIdx.x;  // 16*16384
    int e = tid & 16383;
    int job = tid >> 14;
    int l = job >> 3, m = job & 7;
    int lane = (e >> 3) & 63;
    int j = e & 7;
    int knb = e >> 9;  // 0..31
    int k = (knb >> 3) * 32 + ((lane >> 4) & 3) * 8 + j;
    int n = (knb & 7) * 16 + (lane & 15);
    long off = (long)k * H + n;
    float v;
    if (m < 3) v = Wl[((long)(l * 5 + m)) * (H * H) + off];
    else if (m == 3) v = Wr[((long)(l * 5 + 0)) * (H * H) + off] +
                         Wr[((long)(l * 5 + 1)) * (H * H) + off] +
                         Wr[((long)(l * 5 + 2)) * (H * H) + off];
    else if (m == 4) v = Wl[((long)(l * 5 + 3)) * (H * H) + off];
    else if (m == 5) v = Wr[((long)(l * 5 + 3)) * (H * H) + off];
    else if (m == 6) v = Wl[((long)(l * 5 + 4)) * (H * H) + off];
    else             v = Wr[((long)(l * 5 + 4)) * (H * H) + off];
    out[(long)job * 16384 + e] = f2b(v);
}

// ---------------- paper bias sums ----------------
__global__ void bsum_kernel(const float* __restrict__ bl, float* __restrict__ bsum_p) {
    int t = threadIdx.x;  // 256
    int l = t >> 7, i = t & 127;
    bsum_p[t] = bl[(long)(l * 5 + 0) * H + i] + bl[(long)(l * 5 + 1) * H + i] +
                bl[(long)(l * 5 + 2) * H + i];
}

// ---------------- edge decode over 5 concatenated relations ----------------
__device__ __forceinline__ void edge_map(long e, const int* w, const int* c, const int* p,
                                         const int* rw, const int* rp2, int half,
                                         int& val, int& bse) {
    if (e < 2 * EWC) {
        if (e < EWC) { val = w[e + (long)half * EWC]; bse = 0; }
        else { val = c[(e - EWC) + (long)half * EWC]; bse = NPC; }
    } else if (e < 2 * EWC + EPC) {
        val = p[(e - 2 * EWC) + (long)half * EPC]; bse = 2 * NPC;
    } else if (e < 3 * EWC + EPC) {
        val = rw[(e - 2 * EWC - EPC) + (long)half * EWC]; bse = 3 * NPC;
    } else {
        val = rp2[(e - 3 * EWC - EPC) + (long)half * EPC]; bse = 3 * NPC + NAC;
    }
}

// ---------------- generic scan machinery (1024 elems / block) ----------------
__global__ void scan_reduce(const int* __restrict__ deg, int* __restrict__ bsum, int n) {
    __shared__ int sdata[256];
    int b = blockIdx.x, t = threadIdx.x;
    int base = b * 1024;
    int s = 0;
#pragma unroll
    for (int j = 0; j < 4; ++j) {
        int i = base + t * 4 + j;
        if (i < n) s += deg[i];
    }
    sdata[t] = s;
    __syncthreads();
    for (int o = 128; o > 0; o >>= 1) {
        if (t < o) sdata[t] += sdata[t + o];
        __syncthreads();
    }
    if (t == 0) bsum[b] = sdata[0];
}

__global__ void scan_bsum(int* __restrict__ bsum, int nb) {
    if (threadIdx.x == 0 && blockIdx.x == 0) {
        int acc = 0;
        for (int i = 0; i < nb; ++i) {
            int v = bsum[i];
            bsum[i] = acc;
            acc += v;
        }
    }
}

__global__ void scan_final(const int* __restrict__ deg, const int* __restrict__ bsum,
                           int* __restrict__ row_ptr, int n, int E) {
    __shared__ int ssum[256];
    int b = blockIdx.x, t = threadIdx.x;
    int base = b * 1024;
    int v[4];
    int s = 0;
#pragma unroll
    for (int j = 0; j < 4; ++j) {
        int i = base + t * 4 + j;
        v[j] = (i < n) ? deg[i] : 0;
        s += v[j];
    }
    ssum[t] = s;
    __syncthreads();
    for (int o = 1; o < 256; o <<= 1) {
        int x = (t >= o) ? ssum[t - o] : 0;
        __syncthreads();
        ssum[t] += x;
        __syncthreads();
    }
    int excl = bsum[b] + ((t > 0) ? ssum[t - 1] : 0);
#pragma unroll
    for (int j = 0; j < 4; ++j) {
        int i = base + t * 4 + j;
        if (i < n) {
            row_ptr[i] = excl;
            excl += v[j];
        }
    }
    if (b == 0 && t == 0) row_ptr[n] = E;
}

// ---------------- pass1a: per-block 256-bucket histogram ----------------
__global__ __launch_bounds__(256) void hist1(const int* __restrict__ w, const int* __restrict__ c,
                                             const int* __restrict__ p, const int* __restrict__ rw,
                                             const int* __restrict__ rp2, int* __restrict__ bh) {
    __shared__ int lh[256];
    int t = threadIdx.x, blk = blockIdx.x;
    lh[t] = 0;
    __syncthreads();
    long e0 = (long)blk * EPB1;
    for (int i = t; i < EPB1; i += 256) {
        int d, b;
        edge_map(e0 + i, w, c, p, rw, rp2, 1, d, b);
        atomicAdd(&lh[(b + d) / CBW2], 1);
    }
    __syncthreads();
    bh[t * NB1 + blk] = lh[t];  // bucket-major for the scan
}

// ---------------- pass1b: LDS-sort chunk by bucket, write runs contiguously ----------------
__global__ __launch_bounds__(256) void scatter1(const int* __restrict__ w, const int* __restrict__ c,
                                                const int* __restrict__ p, const int* __restrict__ rw,
                                                const int* __restrict__ rp2,
                                                const int* __restrict__ bhscan,
                                                u64* __restrict__ binned) {
    __shared__ u64 sorted[EPB1];
    __shared__ int lh[256];     // hist then cursor
    __shared__ int lofs[256];   // local exclusive offsets
    __shared__ int gbase[256];
    int t = threadIdx.x, blk = blockIdx.x;
    lh[t] = 0;
    gbase[t] = bhscan[t * NB1 + blk];
    __syncthreads();
    long e0 = (long)blk * EPB1;
    for (int i = t; i < EPB1; i += 256) {
        int d, b;
        edge_map(e0 + i, w, c, p, rw, rp2, 1, d, b);
        atomicAdd(&lh[(b + d) / CBW2], 1);
    }
    __syncthreads();
    int own = lh[t];
    lofs[t] = own;
    __syncthreads();
    for (int o = 1; o < 256; o <<= 1) {
        int v = (t >= o) ? lofs[t - o] : 0;
        __syncthreads();
        lofs[t] += v;
        __syncthreads();
    }
    int excl = lofs[t] - own;
    __syncthreads();
    lofs[t] = excl;
    lh[t] = excl;  // cursor
    __syncthreads();
    for (int i = t; i < EPB1; i += 256) {
        int d, b, s, b2;
        edge_map(e0 + i, w, c, p, rw, rp2, 1, d, b);
        edge_map(e0 + i, w, c, p, rw, rp2, 0, s, b2);
        int g = b + d;
        int pos = atomicAdd(&lh[g / CBW2], 1);
        sorted[pos] = ((u64)(unsigned)g << 32) | (unsigned)s;
    }
    __syncthreads();
    for (int i = t; i < EPB1; i += 256) {
        u64 ent = sorted[i];
        int g = (int)(ent >> 32);
        int bk = g / CBW2;
        binned[(long)gbase[bk] + (i - lofs[bk])] = ent;
    }
}

// ---------------- pass2: per-bucket LDS hist+scan -> gscan, place srcs ----------------
__global__ __launch_bounds__(256) void pass2(const u64* __restrict__ binned,
                                             const int* __restrict__ bhscan,
                                             int* __restrict__ gscan,
                                             int* __restrict__ srcs_all) {
    __shared__ int cnt[CBW2];
    __shared__ int exc[CBW2];
    __shared__ int psum[256];
    int cb = blockIdx.x, t = threadIdx.x;
    int n0 = cb * CBW2;
    int n1 = n0 + CBW2;
    if (n1 > NDEG) n1 = NDEG;
    int nn = n1 - n0;
    for (int i = t; i < nn; i += 256) cnt[i] = 0;
    __syncthreads();
    int e0 = bhscan[cb * NB1];
    int e1 = (cb == 255) ? ETOT : bhscan[(cb + 1) * NB1];
    for (int e = e0 + t; e < e1; e += 256) {
        int g = (int)(binned[e] >> 32);
        atomicAdd(&cnt[g - n0], 1);
    }
    __syncthreads();
    int o0 = t * 11;  // 256*11 = 2816 >= 2774
    int s = 0;
#pragma unroll
    for (int k = 0; k < 11; ++k) {
        int i = o0 + k;
        int v = (i < nn) ? cnt[i] : 0;
        if (i < CBW2) exc[i] = s;
        s += v;
    }
    psum[t] = s;
    __syncthreads();
    for (int o = 1; o < 256; o <<= 1) {
        int v = (t >= o) ? psum[t - o] : 0;
        __syncthreads();
        psum[t] += v;
        __syncthreads();
    }
    int eoff = psum[t] - s;
#pragma unroll
    for (int k = 0; k < 11; ++k) {
        int i = o0 + k;
        if (i < CBW2) exc[i] += eoff;
    }
    __syncthreads();
    for (int i = t; i < nn; i += 256) {
        gscan[n0 + i] = e0 + exc[i];
        cnt[i] = 0;
    }
    if (cb == 255 && t == 0) gscan[NDEG] = ETOT;
    __syncthreads();
    for (int e = e0 + t; e < e1; e += 256) {
        u64 v = binned[e];
        int g = (int)(v >> 32);
        int s2 = (int)(v & 0xffffffffu);
        int loc = g - n0;
        int pos = atomicAdd(&cnt[loc], 1);
        srcs_all[e0 + exc[loc] + pos] = s2;
    }
}

// ---------------- zgemm3: dual-output job (A shared) + 2 single jobs ----------------
// blocks [0,t0): A=a0, outputs o0a=A@w0a and o0b=A@w0b (A fragments loaded once)
// blocks [t0,t0+t1): A=a1 -> o1 ; rest: A=a2 -> o2
__global__ __launch_bounds__(256) void zgemm3(
    const u16* __restrict__ a0, const u16* __restrict__ w0a, const u16* __restrict__ w0b,
    u16* __restrict__ o0a, u16* __restrict__ o0b, int t0,
    const u16* __restrict__ a1, const u16* __restrict__ w1, u16* __restrict__ o1, int t1,
    const u16* __restrict__ a2, const u16* __restrict__ w2, u16* __restrict__ o2) {
    const int b = blockIdx.x;
    const int t = threadIdx.x;
    const int lane = t & 63;
    const int w = t >> 6;
    const int wr = w >> 1, wc = w & 1;
    const int hi = (lane >> 4) & 3;
    const int lo = lane & 15;

    if (b < t0) {
        const long base = (long)b * 128;
        f32x4 acc0[4][4], acc1[4][4];
#pragma unroll
        for (int i = 0; i < 4; ++i)
#pragma unroll
            for (int j = 0; j < 4; ++j) {
                acc0[i][j] = (f32x4){0.f, 0.f, 0.f, 0.f};
                acc1[i][j] = (f32x4){0.f, 0.f, 0.f, 0.f};
            }
#pragma unroll
        for (int ks = 0; ks < 4; ++ks) {
            bf16x8 a[4];
#pragma unroll
            for (int fr = 0; fr < 4; ++fr) {
                long r = base + wr * 64 + fr * 16 + lo;
                a[fr] = *reinterpret_cast<const bf16x8*>(a0 + r * H + ks * 32 + hi * 8);
            }
#pragma unroll
            for (int fc = 0; fc < 4; ++fc) {
                int nb = wc * 4 + fc;
                bf16x8 ba = *reinterpret_cast<const bf16x8*>(w0a + ((ks * 8 + nb) * 512 + lane * 8));
                bf16x8 bb = *reinterpret_cast<const bf16x8*>(w0b + ((ks * 8 + nb) * 512 + lane * 8));
#pragma unroll
                for (int fr = 0; fr < 4; ++fr) {
                    acc0[fr][fc] = __builtin_amdgcn_mfma_f32_16x16x32_bf16(a[fr], ba, acc0[fr][fc], 0, 0, 0);
                    acc1[fr][fc] = __builtin_amdgcn_mfma_f32_16x16x32_bf16(a[fr], bb, acc1[fr][fc], 0, 0, 0);
                }
            }
        }
#pragma unroll
        for (int fc = 0; fc < 4; ++fc) {
            int col = wc * 64 + fc * 16 + lo;
#pragma unroll
            for (int fr = 0; fr < 4; ++fr) {
#pragma unroll
                for (int i = 0; i < 4; ++i) {
                    long g = base + wr * 64 + fr * 16 + hi * 4 + i;
                    o0a[g * H + col] = f2b(acc0[fr][fc][i]);
                    o0b[g * H + col] = f2b(acc1[fr][fc][i]);
                }
            }
        }
    } else {
        const u16 *A, *W;
        u16* O;
        int lb;
        if (b < t0 + t1) { A = a1; W = w1; O = o1; lb = b - t0; }
        else             { A = a2; W = w2; O = o2; lb = b - t0 - t1; }
        const long base = (long)lb * 128;
        f32x4 acc[4][4];
#pragma unroll
        for (int i = 0; i < 4; ++i)
#pragma unroll
            for (int j = 0; j < 4; ++j) acc[i][j] = (f32x4){0.f, 0.f, 0.f, 0.f};
#pragma unroll
        for (int ks = 0; ks < 4; ++ks) {
            bf16x8 a[4];
#pragma unroll
            for (int fr = 0; fr < 4; ++fr) {
                long r = base + wr * 64 + fr * 16 + lo;
                a[fr] = *reinterpret_cast<const bf16x8*>(A + r * H + ks * 32 + hi * 8);
            }
#pragma unroll
            for (int fc = 0; fc < 4; ++fc) {
                int nb = wc * 4 + fc;
                bf16x8 bb = *reinterpret_cast<const bf16x8*>(W + ((ks * 8 + nb) * 512 + lane * 8));
#pragma unroll
                for (int fr = 0; fr < 4; ++fr)
                    acc[fr][fc] = __builtin_amdgcn_mfma_f32_16x16x32_bf16(a[fr], bb, acc[fr][fc], 0, 0, 0);
            }
        }
#pragma unroll
        for (int fc = 0; fc < 4; ++fc) {
            int col = wc * 64 + fc * 16 + lo;
#pragma unroll
            for (int fr = 0; fr < 4; ++fr) {
#pragma unroll
                for (int i = 0; i < 4; ++i) {
                    long g = base + wr * 64 + fr * 16 + hi * 4 + i;
                    O[g * H + col] = f2b(acc[fr][fc][i]);
                }
            }
        }
    }
}

// ---------------- final gather core (ILP-2: two loads in flight) ----------------
__device__ __forceinline__ void acc_u4(const uint4& v, float t[8]) {
    t[0] += b2f((u16)(v.x & 0xffff)); t[1] += b2f((u16)(v.x >> 16));
    t[2] += b2f((u16)(v.y & 0xffff)); t[3] += b2f((u16)(v.y >> 16));
    t[4] += b2f((u16)(v.z & 0xffff)); t[5] += b2f((u16)(v.z >> 16));
    t[6] += b2f((u16)(v.w & 0xffff)); t[7] += b2f((u16)(v.w >> 16));
}

__device__ __forceinline__ void acc_mean(const u16* __restrict__ z,
                                         const int* __restrict__ ss,
                                         int beg, int end, int lane, int q, int l16,
                                         float ax[8]) {
    float t[8];
#pragma unroll
    for (int i = 0; i < 8; ++i) t[i] = 0.f;
    for (int c = beg; c < end; c += 64) {
        int m = end - c;
        if (m > 64) m = 64;
        int idx = (lane < m) ? ss[c + lane] : 0;
        for (int jj = 0; jj < m; jj += 8) {
            int s0 = __shfl(idx, jj + q, 64);
            int s1 = __shfl(idx, jj + 4 + q, 64);
            bool p0 = (jj + q < m), p1 = (jj + 4 + q < m);
            uint4 v0, v1;
            if (p0) v0 = *reinterpret_cast<const uint4*>(z + (long)s0 * H + l16 * 8);
            if (p1) v1 = *reinterpret_cast<const uint4*>(z + (long)s1 * H + l16 * 8);
            if (p0) acc_u4(v0, t);
            if (p1) acc_u4(v1, t);
        }
    }
    float inv = 1.0f / fmaxf((float)(end - beg), 1.0f);
#pragma unroll
    for (int i = 0; i < 8; ++i) ax[i] += t[i] * inv;
}

__device__ __forceinline__ void final_write(float ax[8], const u16* zself, long w,
                                            const float* __restrict__ bias, float scale,
                                            float* yf, u16* yb, int lane, int q, int l16) {
#pragma unroll
    for (int i = 0; i < 8; ++i) {
        ax[i] += __shfl_xor(ax[i], 32, 64);
        ax[i] += __shfl_xor(ax[i], 16, 64);
    }
    if (q == 0) {
        const uint4 sv = *reinterpret_cast<const uint4*>(zself + w * H + l16 * 8);
        float se[8] = {b2f((u16)(sv.x & 0xffff)), b2f((u16)(sv.x >> 16)),
                       b2f((u16)(sv.y & 0xffff)), b2f((u16)(sv.y >> 16)),
                       b2f((u16)(sv.z & 0xffff)), b2f((u16)(sv.z >> 16)),
                       b2f((u16)(sv.w & 0xffff)), b2f((u16)(sv.w >> 16))};
        const float4 b0 = *reinterpret_cast<const float4*>(bias + l16 * 8);
        const float4 b1 = *reinterpret_cast<const float4*>(bias + l16 * 8 + 4);
        float bb[8] = {b0.x, b0.y, b0.z, b0.w, b1.x, b1.y, b1.z, b1.w};
        float o[8];
#pragma unroll
        for (int i = 0; i < 8; ++i) o[i] = fmaxf((ax[i] + se[i] + bb[i]) * scale, 0.f);
        if (yf) {
            float* yp = yf + w * H + l16 * 8;
            *reinterpret_cast<float4*>(yp) = make_float4(o[0], o[1], o[2], o[3]);
            *reinterpret_cast<float4*>(yp + 4) = make_float4(o[4], o[5], o[6], o[7]);
        } else {
            uint4 ov;
            ov.x = (unsigned)f2b(o[0]) | ((unsigned)f2b(o[1]) << 16);
            ov.y = (unsigned)f2b(o[2]) | ((unsigned)f2b(o[3]) << 16);
            ov.z = (unsigned)f2b(o[4]) | ((unsigned)f2b(o[5]) << 16);
            ov.w = (unsigned)f2b(o[6]) | ((unsigned)f2b(o[7]) << 16);
            *reinterpret_cast<uint4*>(yb + w * H + l16 * 8) = ov;
        }
    }
}

// paper: 3 relations + self, scale 1/3
__global__ void final_paper(const u16* __restrict__ z0, const u16* __restrict__ z1,
                            const u16* __restrict__ z2, const u16* __restrict__ zps,
                            const int* __restrict__ gs, const int* __restrict__ ss,
                            const float* __restrict__ bias,
                            float* yf, u16* yb) {
    long gid = (long)blockIdx.x * blockDim.x + threadIdx.x;
    long w = gid >> 6;
    if (w >= NPC) return;
    int lane = (int)(gid & 63), q = lane >> 4, l16 = lane & 15;
    float ax[8] = {0.f, 0.f, 0.f, 0.f, 0.f, 0.f, 0.f, 0.f};
    acc_mean(z0, ss, gs[w], gs[w + 1], lane, q, l16, ax);
    acc_mean(z1, ss, gs[NPC + w], gs[NPC + w + 1], lane, q, l16, ax);
    acc_mean(z2, ss, gs[2 * NPC + w], gs[2 * NPC + w + 1], lane, q, l16, ax);
    final_write(ax, zps, w, bias, 1.0f / 3.0f, yf, yb, lane, q, l16);
}

// author + venue fused: 1 relation + self each, scale 1
__global__ void final_av(const u16* __restrict__ z3, const u16* __restrict__ zas,
                         const u16* __restrict__ z4, const u16* __restrict__ zvs,
                         const int* __restrict__ rp, const int* __restrict__ ss,
                         const float* __restrict__ bias3, const float* __restrict__ bias4,
                         float* yfa, u16* yba, float* yfv, u16* ybv) {
    long gid = (long)blockIdx.x * blockDim.x + threadIdx.x;
    long w = gid >> 6;
    if (w >= NAC + NVC) return;
    int lane = (int)(gid & 63), q = lane >> 4, l16 = lane & 15;
    float ax[8] = {0.f, 0.f, 0.f, 0.f, 0.f, 0.f, 0.f, 0.f};
    if (w < NAC) {
        acc_mean(z3, ss, rp[w], rp[w + 1], lane, q, l16, ax);
        final_write(ax, zas, w, bias3, 1.0f, yfa, yba, lane, q, l16);
    } else {
        long wv = w - NAC;
        acc_mean(z4, ss, rp[NAC + wv], rp[NAC + wv + 1], lane, q, l16, ax);
        final_write(ax, zvs, wv, bias4, 1.0f, yfv, ybv, lane, q, l16);
    }
}

extern "C" void kernel_launch(void* const* d_in, const int* in_sizes, int n_in,
                              void* d_out, int out_size, void* d_ws, size_t ws_size,
                              hipStream_t stream) {
    const float* xp0 = (const float*)d_in[0];
    const float* xa0 = (const float*)d_in[1];
    const float* xv0 = (const float*)d_in[2];
    const float* Wl  = (const float*)d_in[3];
    const float* bl  = (const float*)d_in[4];
    const float* Wr  = (const float*)d_in[5];
    const int* ei_w  = (const int*)d_in[6];
    const int* ei_c  = (const int*)d_in[7];
    const int* ei_p  = (const int*)d_in[8];
    const int* ei_rw = (const int*)d_in[9];
    const int* ei_rp = (const int*)d_in[10];

    char* cur = (char*)d_ws;
    auto alloc = [&](long bytes) { char* r = cur; cur += (bytes + 255) & ~255L; return r; };
    u16* xpb   = (u16*)alloc((long)NPP * H * 2);
    u16* xab   = (u16*)alloc((long)NAP * H * 2);
    u16* xvb   = (u16*)alloc((long)NVP * H * 2);
    u16* packw = (u16*)alloc(16 * 16384 * 2);
    float* bsum_p = (float*)alloc(256 * 4);
    int* gscan    = (int*)alloc((NDEG + 1) * 4);
    int* srcs_all = (int*)alloc((long)ETOT * 4);
    int* bh       = (int*)alloc((long)NSC * 4);        // 2 MB
    int* bhscan   = (int*)alloc((long)(NSC + 1) * 4);  // 2 MB
    int* bsums    = (int*)alloc(((NSC + 1023) / 1024) * 4);
    u16* Z        = (u16*)alloc((long)(2 * NPP + NAP + NVP) * H * 2);  // 130.6 MB

    // binned aliases Z (dead during CSR build): ETOT*8 = 51.2 MB << 130.6 MB
    u64* binned = (u64*)Z;

    // Z job pointers (shared across phases)
    u16* zj0 = Z;
    u16* zj1 = Z + (long)NPP * H;
    u16* zj2 = Z + (long)(NPP + NAP) * H;
    u16* zj3 = Z + (long)(2 * NPP + NAP) * H;

    // layer-0 output stage in d_out (bf16), overwritten last by layer-1 paper final
    u16* sp = (u16*)d_out;
    u16* sa = sp + (long)NPP * H;
    u16* sv = sa + (long)NAP * H;

    float* op = (float*)d_out;
    float* oa = op + (long)NPC * H;
    float* ov = oa + (long)NAC * H;

    // ---- prep ----
    cast_kernel<<<2048, 256, 0, stream>>>(xp0, xpb, (long)NPC * H / 4);
    cast_kernel<<<1024, 256, 0, stream>>>(xa0, xab, (long)NAC * H / 4);
    cast_kernel<<<256, 256, 0, stream>>>(xv0, xvb, (long)NVC * H / 4);
    pack_kernel<<<1024, 256, 0, stream>>>(Wl, Wr, packw);
    bsum_kernel<<<1, 256, 0, stream>>>(bl, bsum_p);

    // ---- CSR build: radix partition ----
    hist1<<<NB1, 256, 0, stream>>>(ei_w, ei_c, ei_p, ei_rw, ei_rp, bh);
    int nb = (NSC + 1023) / 1024;  // 512
    scan_reduce<<<nb, 256, 0, stream>>>(bh, bsums, NSC);
    scan_bsum<<<1, 64, 0, stream>>>(bsums, nb);
    scan_final<<<nb, 256, 0, stream>>>(bh, bsums, bhscan, NSC, ETOT);
    scatter1<<<NB1, 256, 0, stream>>>(ei_w, ei_c, ei_p, ei_rw, ei_rp, bhscan, binned);
    pass2<<<256, 256, 0, stream>>>(binned, bhscan, gscan, srcs_all);

    auto PW = [&](int l, int m) { return packw + (long)(l * 8 + m) * 16384; };
    const int NT = TP + TA + TV;  // 2424
    auto GVB = [&](long n) { return (int)((n * 64 + 255) / 256); };

    auto run_layer = [&](int l, const u16* xp, const u16* xa, const u16* xv,
                         float* yfp, u16* ybp, float* yfa, u16* yba,
                         float* yfv, u16* ybv) {
        // phase BC: dual A=xp -> z3(zj0)=xp@Wl3, z4(zj2)=xp@Wl4; zas(zj1)=xa@Wr3; zvs(zj3)=xv@Wr4
        zgemm3<<<NT, 256, 0, stream>>>(xp, PW(l, 4), PW(l, 6), zj0, zj2, TP,
                                       xa, PW(l, 5), zj1, TA,
                                       xv, PW(l, 7), zj3);
        final_av<<<GVB(NAC + NVC), 256, 0, stream>>>(
            zj0, zj1, zj2, zj3, gscan + 3 * NPC, srcs_all,
            bl + (long)(l * 5 + 3) * H, bl + (long)(l * 5 + 4) * H,
            yfa, yba, yfv, ybv);
        // phase A: dual A=xp -> zps(zj0)=xp@sumWr, z1(zj2)=xp@Wl1; z0(zj1)=xa@Wl0; z2(zj3)=xv@Wl2
        zgemm3<<<NT, 256, 0, stream>>>(xp, PW(l, 3), PW(l, 1), zj0, zj2, TP,
                                       xa, PW(l, 0), zj1, TA,
                                       xv, PW(l, 2), zj3);
        final_paper<<<GVB(NPC), 256, 0, stream>>>(
            zj1, zj2, zj3, zj0, gscan, srcs_all, bsum_p + l * 128, yfp, ybp);
    };

    // layer 0: bf16 outputs staged in d_out
    run_layer(0, xpb, xab, xvb, nullptr, sp, nullptr, sa, nullptr, sv);
    // layer 1: f32 outputs into d_out (paper final last, overwrites stage after all reads)
    run_layer(1, sp, sa, sv, op, nullptr, oa, nullptr, ov, nullptr);
}

// Round 14
// 1059.328 us; speedup vs baseline: 1.5278x; 1.0245x over previous
//
#include <hip/hip_runtime.h>

#define H 128
typedef unsigned short u16;
typedef unsigned long long u64;
typedef __attribute__((ext_vector_type(8))) short bf16x8;
typedef __attribute__((ext_vector_type(4))) float f32x4;

#define NPC 200000
#define NAC 100000
#define NVC 10000
#define EWC 2000000
#define EPC 200000
#define ETOT 6400000
#define NDEG 710000
#define NPP 200064
#define NAP 100096
#define NVP 10112
#define TP 1563
#define TA 782
#define TV 79
#define CBW2 2774     // nodes per coarse bucket (256*2774 = 710144 >= NDEG)
#define NB1 2048      // pass1 blocks
#define EPB1 3125     // edges per pass1 block (2048*3125 == ETOT)
#define NSC (256 * NB1)

__device__ __forceinline__ u16 f2b(float f) {
    unsigned u = __builtin_bit_cast(unsigned, f);
    unsigned r = (u + 0x7fff + ((u >> 16) & 1)) >> 16;
    return (u16)r;
}
__device__ __forceinline__ float b2f(u16 b) {
    unsigned u = ((unsigned)b) << 16;
    return __builtin_bit_cast(float, u);
}

// ---------------- cast f32 -> bf16 ----------------
__global__ void cast_kernel(const float* __restrict__ in, u16* __restrict__ out, long n4) {
    long stride = (long)gridDim.x * blockDim.x;
    for (long i = (long)blockIdx.x * blockDim.x + threadIdx.x; i < n4; i += stride) {
        float4 v = reinterpret_cast<const float4*>(in)[i];
        ushort4 o;
        o.x = f2b(v.x); o.y = f2b(v.y); o.z = f2b(v.z); o.w = f2b(v.w);
        reinterpret_cast<ushort4*>(out)[i] = o;
    }
}

// ---------------- pack weights into MFMA B-fragment layout (bf16) ----------------
// Fragment->logical-column map: n = (lane&15)*8 + nb  (so a thread's 4 fc values
// are 4 consecutive logical cols -> 8B packed epilogue stores in zgemm).
// jobs m: 0-2: Wl[l,m]; 3: sum Wr[l,0..2]; 4: Wl[l,3]; 5: Wr[l,3]; 6: Wl[l,4]; 7: Wr[l,4]
__global__ void pack_kernel(const float* __restrict__ Wl, const float* __restrict__ Wr,
                            u16* __restrict__ out) {
    int tid = blockIdx.x * blockDim.x + threadIdx.x;  // 16*16384
    int e = tid & 16383;
    int job = tid >> 14;
    int l = job >> 3, m = job & 7;
    int lane = (e >> 3) & 63;
    int j = e & 7;
    int knb = e >> 9;  // 0..31
    int k = (knb >> 3) * 32 + ((lane >> 4) & 3) * 8 + j;
    int n = (lane & 15) * 8 + (knb & 7);
    long off = (long)k * H + n;
    float v;
    if (m < 3) v = Wl[((long)(l * 5 + m)) * (H * H) + off];
    else if (m == 3) v = Wr[((long)(l * 5 + 0)) * (H * H) + off] +
                         Wr[((long)(l * 5 + 1)) * (H * H) + off] +
                         Wr[((long)(l * 5 + 2)) * (H * H) + off];
    else if (m == 4) v = Wl[((long)(l * 5 + 3)) * (H * H) + off];
    else if (m == 5) v = Wr[((long)(l * 5 + 3)) * (H * H) + off];
    else if (m == 6) v = Wl[((long)(l * 5 + 4)) * (H * H) + off];
    else             v = Wr[((long)(l * 5 + 4)) * (H * H) + off];
    out[(long)job * 16384 + e] = f2b(v);
}

// ---------------- paper bias sums ----------------
__global__ void bsum_kernel(const float* __restrict__ bl, float* __restrict__ bsum_p) {
    int t = threadIdx.x;  // 256
    int l = t >> 7, i = t & 127;
    bsum_p[t] = bl[(long)(l * 5 + 0) * H + i] + bl[(long)(l * 5 + 1) * H + i] +
                bl[(long)(l * 5 + 2) * H + i];
}

// ---------------- edge decode over 5 concatenated relations ----------------
__device__ __forceinline__ void edge_map(long e, const int* w, const int* c, const int* p,
                                         const int* rw, const int* rp2, int half,
                                         int& val, int& bse) {
    if (e < 2 * EWC) {
        if (e < EWC) { val = w[e + (long)half * EWC]; bse = 0; }
        else { val = c[(e - EWC) + (long)half * EWC]; bse = NPC; }
    } else if (e < 2 * EWC + EPC) {
        val = p[(e - 2 * EWC) + (long)half * EPC]; bse = 2 * NPC;
    } else if (e < 3 * EWC + EPC) {
        val = rw[(e - 2 * EWC - EPC) + (long)half * EWC]; bse = 3 * NPC;
    } else {
        val = rp2[(e - 3 * EWC - EPC) + (long)half * EPC]; bse = 3 * NPC + NAC;
    }
}

// ---------------- generic scan machinery (1024 elems / block) ----------------
__global__ void scan_reduce(const int* __restrict__ deg, int* __restrict__ bsum, int n) {
    __shared__ int sdata[256];
    int b = blockIdx.x, t = threadIdx.x;
    int base = b * 1024;
    int s = 0;
#pragma unroll
    for (int j = 0; j < 4; ++j) {
        int i = base + t * 4 + j;
        if (i < n) s += deg[i];
    }
    sdata[t] = s;
    __syncthreads();
    for (int o = 128; o > 0; o >>= 1) {
        if (t < o) sdata[t] += sdata[t + o];
        __syncthreads();
    }
    if (t == 0) bsum[b] = sdata[0];
}

__global__ void scan_bsum(int* __restrict__ bsum, int nb) {
    if (threadIdx.x == 0 && blockIdx.x == 0) {
        int acc = 0;
        for (int i = 0; i < nb; ++i) {
            int v = bsum[i];
            bsum[i] = acc;
            acc += v;
        }
    }
}

__global__ void scan_final(const int* __restrict__ deg, const int* __restrict__ bsum,
                           int* __restrict__ row_ptr, int n, int E) {
    __shared__ int ssum[256];
    int b = blockIdx.x, t = threadIdx.x;
    int base = b * 1024;
    int v[4];
    int s = 0;
#pragma unroll
    for (int j = 0; j < 4; ++j) {
        int i = base + t * 4 + j;
        v[j] = (i < n) ? deg[i] : 0;
        s += v[j];
    }
    ssum[t] = s;
    __syncthreads();
    for (int o = 1; o < 256; o <<= 1) {
        int x = (t >= o) ? ssum[t - o] : 0;
        __syncthreads();
        ssum[t] += x;
        __syncthreads();
    }
    int excl = bsum[b] + ((t > 0) ? ssum[t - 1] : 0);
#pragma unroll
    for (int j = 0; j < 4; ++j) {
        int i = base + t * 4 + j;
        if (i < n) {
            row_ptr[i] = excl;
            excl += v[j];
        }
    }
    if (b == 0 && t == 0) row_ptr[n] = E;
}

// ---------------- pass1a: per-block 256-bucket histogram ----------------
__global__ __launch_bounds__(256) void hist1(const int* __restrict__ w, const int* __restrict__ c,
                                             const int* __restrict__ p, const int* __restrict__ rw,
                                             const int* __restrict__ rp2, int* __restrict__ bh) {
    __shared__ int lh[256];
    int t = threadIdx.x, blk = blockIdx.x;
    lh[t] = 0;
    __syncthreads();
    long e0 = (long)blk * EPB1;
    for (int i = t; i < EPB1; i += 256) {
        int d, b;
        edge_map(e0 + i, w, c, p, rw, rp2, 1, d, b);
        atomicAdd(&lh[(b + d) / CBW2], 1);
    }
    __syncthreads();
    bh[t * NB1 + blk] = lh[t];  // bucket-major for the scan
}

// ---------------- pass1b: LDS-sort chunk by bucket, write runs contiguously ----------------
__global__ __launch_bounds__(256) void scatter1(const int* __restrict__ w, const int* __restrict__ c,
                                                const int* __restrict__ p, const int* __restrict__ rw,
                                                const int* __restrict__ rp2,
                                                const int* __restrict__ bhscan,
                                                u64* __restrict__ binned) {
    __shared__ u64 sorted[EPB1];
    __shared__ int lh[256];     // hist then cursor
    __shared__ int lofs[256];   // local exclusive offsets
    __shared__ int gbase[256];
    int t = threadIdx.x, blk = blockIdx.x;
    lh[t] = 0;
    gbase[t] = bhscan[t * NB1 + blk];
    __syncthreads();
    long e0 = (long)blk * EPB1;
    for (int i = t; i < EPB1; i += 256) {
        int d, b;
        edge_map(e0 + i, w, c, p, rw, rp2, 1, d, b);
        atomicAdd(&lh[(b + d) / CBW2], 1);
    }
    __syncthreads();
    int own = lh[t];
    lofs[t] = own;
    __syncthreads();
    for (int o = 1; o < 256; o <<= 1) {
        int v = (t >= o) ? lofs[t - o] : 0;
        __syncthreads();
        lofs[t] += v;
        __syncthreads();
    }
    int excl = lofs[t] - own;
    __syncthreads();
    lofs[t] = excl;
    lh[t] = excl;  // cursor
    __syncthreads();
    for (int i = t; i < EPB1; i += 256) {
        int d, b, s, b2;
        edge_map(e0 + i, w, c, p, rw, rp2, 1, d, b);
        edge_map(e0 + i, w, c, p, rw, rp2, 0, s, b2);
        int g = b + d;
        int pos = atomicAdd(&lh[g / CBW2], 1);
        sorted[pos] = ((u64)(unsigned)g << 32) | (unsigned)s;
    }
    __syncthreads();
    for (int i = t; i < EPB1; i += 256) {
        u64 ent = sorted[i];
        int g = (int)(ent >> 32);
        int bk = g / CBW2;
        binned[(long)gbase[bk] + (i - lofs[bk])] = ent;
    }
}

// ---------------- pass2 (512 threads): per-bucket LDS hist+scan -> gscan, place srcs ----------------
__global__ __launch_bounds__(512) void pass2(const u64* __restrict__ binned,
                                             const int* __restrict__ bhscan,
                                             int* __restrict__ gscan,
                                             int* __restrict__ srcs_all) {
    __shared__ int cnt[CBW2];
    __shared__ int exc[CBW2];
    __shared__ int psum[512];
    int cb = blockIdx.x, t = threadIdx.x;
    int n0 = cb * CBW2;
    int n1 = n0 + CBW2;
    if (n1 > NDEG) n1 = NDEG;
    int nn = n1 - n0;
    for (int i = t; i < nn; i += 512) cnt[i] = 0;
    __syncthreads();
    int e0 = bhscan[cb * NB1];
    int e1 = (cb == 255) ? ETOT : bhscan[(cb + 1) * NB1];
    for (int e = e0 + t; e < e1; e += 512) {
        int g = (int)(binned[e] >> 32);
        atomicAdd(&cnt[g - n0], 1);
    }
    __syncthreads();
    int o0 = t * 6;  // 512*6 = 3072 >= 2774
    int s = 0;
#pragma unroll
    for (int k = 0; k < 6; ++k) {
        int i = o0 + k;
        int v = (i < nn) ? cnt[i] : 0;
        if (i < CBW2) exc[i] = s;
        s += v;
    }
    psum[t] = s;
    __syncthreads();
    for (int o = 1; o < 512; o <<= 1) {
        int v = (t >= o) ? psum[t - o] : 0;
        __syncthreads();
        psum[t] += v;
        __syncthreads();
    }
    int eoff = psum[t] - s;
#pragma unroll
    for (int k = 0; k < 6; ++k) {
        int i = o0 + k;
        if (i < CBW2) exc[i] += eoff;
    }
    __syncthreads();
    for (int i = t; i < nn; i += 512) {
        gscan[n0 + i] = e0 + exc[i];
        cnt[i] = 0;
    }
    if (cb == 255 && t == 0) gscan[NDEG] = ETOT;
    __syncthreads();
    for (int e = e0 + t; e < e1; e += 512) {
        u64 v = binned[e];
        int g = (int)(v >> 32);
        int s2 = (int)(v & 0xffffffffu);
        int loc = g - n0;
        int pos = atomicAdd(&cnt[loc], 1);
        srcs_all[e0 + exc[loc] + pos] = s2;
    }
}

// ---------------- zgemm3: dual-output job (A shared) + 2 single jobs ----------------
// Epilogue: packed-column fragment map -> one 8B store per (fr,i) per output.
__global__ __launch_bounds__(256) void zgemm3(
    const u16* __restrict__ a0, const u16* __restrict__ w0a, const u16* __restrict__ w0b,
    u16* __restrict__ o0a, u16* __restrict__ o0b, int t0,
    const u16* __restrict__ a1, const u16* __restrict__ w1, u16* __restrict__ o1, int t1,
    const u16* __restrict__ a2, const u16* __restrict__ w2, u16* __restrict__ o2) {
    const int b = blockIdx.x;
    const int t = threadIdx.x;
    const int lane = t & 63;
    const int w = t >> 6;
    const int wr = w >> 1, wc = w & 1;
    const int hi = (lane >> 4) & 3;
    const int lo = lane & 15;

    if (b < t0) {
        const long base = (long)b * 128;
        f32x4 acc0[4][4], acc1[4][4];
#pragma unroll
        for (int i = 0; i < 4; ++i)
#pragma unroll
            for (int j = 0; j < 4; ++j) {
                acc0[i][j] = (f32x4){0.f, 0.f, 0.f, 0.f};
                acc1[i][j] = (f32x4){0.f, 0.f, 0.f, 0.f};
            }
#pragma unroll
        for (int ks = 0; ks < 4; ++ks) {
            bf16x8 a[4];
#pragma unroll
            for (int fr = 0; fr < 4; ++fr) {
                long r = base + wr * 64 + fr * 16 + lo;
                a[fr] = *reinterpret_cast<const bf16x8*>(a0 + r * H + ks * 32 + hi * 8);
            }
#pragma unroll
            for (int fc = 0; fc < 4; ++fc) {
                int nb = wc * 4 + fc;
                bf16x8 ba = *reinterpret_cast<const bf16x8*>(w0a + ((ks * 8 + nb) * 512 + lane * 8));
                bf16x8 bb = *reinterpret_cast<const bf16x8*>(w0b + ((ks * 8 + nb) * 512 + lane * 8));
#pragma unroll
                for (int fr = 0; fr < 4; ++fr) {
                    acc0[fr][fc] = __builtin_amdgcn_mfma_f32_16x16x32_bf16(a[fr], ba, acc0[fr][fc], 0, 0, 0);
                    acc1[fr][fc] = __builtin_amdgcn_mfma_f32_16x16x32_bf16(a[fr], bb, acc1[fr][fc], 0, 0, 0);
                }
            }
        }
#pragma unroll
        for (int fr = 0; fr < 4; ++fr) {
#pragma unroll
            for (int i = 0; i < 4; ++i) {
                long g = base + wr * 64 + fr * 16 + hi * 4 + i;
                long off = g * H + lo * 8 + wc * 4;
                ushort4 pa, pb;
                pa.x = f2b(acc0[fr][0][i]); pa.y = f2b(acc0[fr][1][i]);
                pa.z = f2b(acc0[fr][2][i]); pa.w = f2b(acc0[fr][3][i]);
                pb.x = f2b(acc1[fr][0][i]); pb.y = f2b(acc1[fr][1][i]);
                pb.z = f2b(acc1[fr][2][i]); pb.w = f2b(acc1[fr][3][i]);
                *reinterpret_cast<ushort4*>(o0a + off) = pa;
                *reinterpret_cast<ushort4*>(o0b + off) = pb;
            }
        }
    } else {
        const u16 *A, *W;
        u16* O;
        int lb;
        if (b < t0 + t1) { A = a1; W = w1; O = o1; lb = b - t0; }
        else             { A = a2; W = w2; O = o2; lb = b - t0 - t1; }
        const long base = (long)lb * 128;
        f32x4 acc[4][4];
#pragma unroll
        for (int i = 0; i < 4; ++i)
#pragma unroll
            for (int j = 0; j < 4; ++j) acc[i][j] = (f32x4){0.f, 0.f, 0.f, 0.f};
#pragma unroll
        for (int ks = 0; ks < 4; ++ks) {
            bf16x8 a[4];
#pragma unroll
            for (int fr = 0; fr < 4; ++fr) {
                long r = base + wr * 64 + fr * 16 + lo;
                a[fr] = *reinterpret_cast<const bf16x8*>(A + r * H + ks * 32 + hi * 8);
            }
#pragma unroll
            for (int fc = 0; fc < 4; ++fc) {
                int nb = wc * 4 + fc;
                bf16x8 bb = *reinterpret_cast<const bf16x8*>(W + ((ks * 8 + nb) * 512 + lane * 8));
#pragma unroll
                for (int fr = 0; fr < 4; ++fr)
                    acc[fr][fc] = __builtin_amdgcn_mfma_f32_16x16x32_bf16(a[fr], bb, acc[fr][fc], 0, 0, 0);
            }
        }
#pragma unroll
        for (int fr = 0; fr < 4; ++fr) {
#pragma unroll
            for (int i = 0; i < 4; ++i) {
                long g = base + wr * 64 + fr * 16 + hi * 4 + i;
                ushort4 pa;
                pa.x = f2b(acc[fr][0][i]); pa.y = f2b(acc[fr][1][i]);
                pa.z = f2b(acc[fr][2][i]); pa.w = f2b(acc[fr][3][i]);
                *reinterpret_cast<ushort4*>(O + g * H + lo * 8 + wc * 4) = pa;
            }
        }
    }
}

// ---------------- final gather core (ILP-4) ----------------
__device__ __forceinline__ void acc_u4(const uint4& v, float t[8]) {
    t[0] += b2f((u16)(v.x & 0xffff)); t[1] += b2f((u16)(v.x >> 16));
    t[2] += b2f((u16)(v.y & 0xffff)); t[3] += b2f((u16)(v.y >> 16));
    t[4] += b2f((u16)(v.z & 0xffff)); t[5] += b2f((u16)(v.z >> 16));
    t[6] += b2f((u16)(v.w & 0xffff)); t[7] += b2f((u16)(v.w >> 16));
}

__device__ __forceinline__ void acc_mean(const u16* __restrict__ z,
                                         const int* __restrict__ ss,
                                         int beg, int end, int lane, int q, int l16,
                                         float ax[8]) {
    float t[8];
#pragma unroll
    for (int i = 0; i < 8; ++i) t[i] = 0.f;
    for (int c = beg; c < end; c += 64) {
        int m = end - c;
        if (m > 64) m = 64;
        int idx = (lane < m) ? ss[c + lane] : 0;
        for (int jj = 0; jj < m; jj += 16) {
            int s0 = __shfl(idx, jj + q, 64);
            int s1 = __shfl(idx, jj + 4 + q, 64);
            int s2 = __shfl(idx, jj + 8 + q, 64);
            int s3 = __shfl(idx, jj + 12 + q, 64);
            bool p0 = (jj + q < m), p1 = (jj + 4 + q < m);
            bool p2 = (jj + 8 + q < m), p3 = (jj + 12 + q < m);
            uint4 v0, v1, v2, v3;
            if (p0) v0 = *reinterpret_cast<const uint4*>(z + (long)s0 * H + l16 * 8);
            if (p1) v1 = *reinterpret_cast<const uint4*>(z + (long)s1 * H + l16 * 8);
            if (p2) v2 = *reinterpret_cast<const uint4*>(z + (long)s2 * H + l16 * 8);
            if (p3) v3 = *reinterpret_cast<const uint4*>(z + (long)s3 * H + l16 * 8);
            if (p0) acc_u4(v0, t);
            if (p1) acc_u4(v1, t);
            if (p2) acc_u4(v2, t);
            if (p3) acc_u4(v3, t);
        }
    }
    float inv = 1.0f / fmaxf((float)(end - beg), 1.0f);
#pragma unroll
    for (int i = 0; i < 8; ++i) ax[i] += t[i] * inv;
}

__device__ __forceinline__ void final_write(float ax[8], const u16* zself, long w,
                                            const float* __restrict__ bias, float scale,
                                            float* yf, u16* yb, int lane, int q, int l16) {
#pragma unroll
    for (int i = 0; i < 8; ++i) {
        ax[i] += __shfl_xor(ax[i], 32, 64);
        ax[i] += __shfl_xor(ax[i], 16, 64);
    }
    if (q == 0) {
        const uint4 sv = *reinterpret_cast<const uint4*>(zself + w * H + l16 * 8);
        float se[8] = {b2f((u16)(sv.x & 0xffff)), b2f((u16)(sv.x >> 16)),
                       b2f((u16)(sv.y & 0xffff)), b2f((u16)(sv.y >> 16)),
                       b2f((u16)(sv.z & 0xffff)), b2f((u16)(sv.z >> 16)),
                       b2f((u16)(sv.w & 0xffff)), b2f((u16)(sv.w >> 16))};
        const float4 b0 = *reinterpret_cast<const float4*>(bias + l16 * 8);
        const float4 b1 = *reinterpret_cast<const float4*>(bias + l16 * 8 + 4);
        float bb[8] = {b0.x, b0.y, b0.z, b0.w, b1.x, b1.y, b1.z, b1.w};
        float o[8];
#pragma unroll
        for (int i = 0; i < 8; ++i) o[i] = fmaxf((ax[i] + se[i] + bb[i]) * scale, 0.f);
        if (yf) {
            float* yp = yf + w * H + l16 * 8;
            *reinterpret_cast<float4*>(yp) = make_float4(o[0], o[1], o[2], o[3]);
            *reinterpret_cast<float4*>(yp + 4) = make_float4(o[4], o[5], o[6], o[7]);
        } else {
            uint4 ov;
            ov.x = (unsigned)f2b(o[0]) | ((unsigned)f2b(o[1]) << 16);
            ov.y = (unsigned)f2b(o[2]) | ((unsigned)f2b(o[3]) << 16);
            ov.z = (unsigned)f2b(o[4]) | ((unsigned)f2b(o[5]) << 16);
            ov.w = (unsigned)f2b(o[6]) | ((unsigned)f2b(o[7]) << 16);
            *reinterpret_cast<uint4*>(yb + w * H + l16 * 8) = ov;
        }
    }
}

// paper: 3 relations + self, scale 1/3
__global__ void final_paper(const u16* __restrict__ z0, const u16* __restrict__ z1,
                            const u16* __restrict__ z2, const u16* __restrict__ zps,
                            const int* __restrict__ gs, const int* __restrict__ ss,
                            const float* __restrict__ bias,
                            float* yf, u16* yb) {
    long gid = (long)blockIdx.x * blockDim.x + threadIdx.x;
    long w = gid >> 6;
    if (w >= NPC) return;
    int lane = (int)(gid & 63), q = lane >> 4, l16 = lane & 15;
    float ax[8] = {0.f, 0.f, 0.f, 0.f, 0.f, 0.f, 0.f, 0.f};
    acc_mean(z0, ss, gs[w], gs[w + 1], lane, q, l16, ax);
    acc_mean(z1, ss, gs[NPC + w], gs[NPC + w + 1], lane, q, l16, ax);
    acc_mean(z2, ss, gs[2 * NPC + w], gs[2 * NPC + w + 1], lane, q, l16, ax);
    final_write(ax, zps, w, bias, 1.0f / 3.0f, yf, yb, lane, q, l16);
}

// author + venue fused: 1 relation + self each, scale 1
__global__ void final_av(const u16* __restrict__ z3, const u16* __restrict__ zas,
                         const u16* __restrict__ z4, const u16* __restrict__ zvs,
                         const int* __restrict__ rp, const int* __restrict__ ss,
                         const float* __restrict__ bias3, const float* __restrict__ bias4,
                         float* yfa, u16* yba, float* yfv, u16* ybv) {
    long gid = (long)blockIdx.x * blockDim.x + threadIdx.x;
    long w = gid >> 6;
    if (w >= NAC + NVC) return;
    int lane = (int)(gid & 63), q = lane >> 4, l16 = lane & 15;
    float ax[8] = {0.f, 0.f, 0.f, 0.f, 0.f, 0.f, 0.f, 0.f};
    if (w < NAC) {
        acc_mean(z3, ss, rp[w], rp[w + 1], lane, q, l16, ax);
        final_write(ax, zas, w, bias3, 1.0f, yfa, yba, lane, q, l16);
    } else {
        long wv = w - NAC;
        acc_mean(z4, ss, rp[NAC + wv], rp[NAC + wv + 1], lane, q, l16, ax);
        final_write(ax, zvs, wv, bias4, 1.0f, yfv, ybv, lane, q, l16);
    }
}

extern "C" void kernel_launch(void* const* d_in, const int* in_sizes, int n_in,
                              void* d_out, int out_size, void* d_ws, size_t ws_size,
                              hipStream_t stream) {
    const float* xp0 = (const float*)d_in[0];
    const float* xa0 = (const float*)d_in[1];
    const float* xv0 = (const float*)d_in[2];
    const float* Wl  = (const float*)d_in[3];
    const float* bl  = (const float*)d_in[4];
    const float* Wr  = (const float*)d_in[5];
    const int* ei_w  = (const int*)d_in[6];
    const int* ei_c  = (const int*)d_in[7];
    const int* ei_p  = (const int*)d_in[8];
    const int* ei_rw = (const int*)d_in[9];
    const int* ei_rp = (const int*)d_in[10];

    char* cur = (char*)d_ws;
    auto alloc = [&](long bytes) { char* r = cur; cur += (bytes + 255) & ~255L; return r; };
    u16* xpb   = (u16*)alloc((long)NPP * H * 2);
    u16* xab   = (u16*)alloc((long)NAP * H * 2);
    u16* xvb   = (u16*)alloc((long)NVP * H * 2);
    u16* packw = (u16*)alloc(16 * 16384 * 2);
    float* bsum_p = (float*)alloc(256 * 4);
    int* gscan    = (int*)alloc((NDEG + 1) * 4);
    int* srcs_all = (int*)alloc((long)ETOT * 4);
    int* bh       = (int*)alloc((long)NSC * 4);        // 2 MB
    int* bhscan   = (int*)alloc((long)(NSC + 1) * 4);  // 2 MB
    int* bsums    = (int*)alloc(((NSC + 1023) / 1024) * 4);
    u16* Z        = (u16*)alloc((long)(2 * NPP + NAP + NVP) * H * 2);  // 130.6 MB

    // binned aliases Z (dead during CSR build): ETOT*8 = 51.2 MB << 130.6 MB
    u64* binned = (u64*)Z;

    // Z job pointers (shared across phases)
    u16* zj0 = Z;
    u16* zj1 = Z + (long)NPP * H;
    u16* zj2 = Z + (long)(NPP + NAP) * H;
    u16* zj3 = Z + (long)(2 * NPP + NAP) * H;

    // layer-0 output stage in d_out (bf16), overwritten last by layer-1 paper final
    u16* sp = (u16*)d_out;
    u16* sa = sp + (long)NPP * H;
    u16* sv = sa + (long)NAP * H;

    float* op = (float*)d_out;
    float* oa = op + (long)NPC * H;
    float* ov = oa + (long)NAC * H;

    // ---- prep ----
    cast_kernel<<<2048, 256, 0, stream>>>(xp0, xpb, (long)NPC * H / 4);
    cast_kernel<<<1024, 256, 0, stream>>>(xa0, xab, (long)NAC * H / 4);
    cast_kernel<<<256, 256, 0, stream>>>(xv0, xvb, (long)NVC * H / 4);
    pack_kernel<<<1024, 256, 0, stream>>>(Wl, Wr, packw);
    bsum_kernel<<<1, 256, 0, stream>>>(bl, bsum_p);

    // ---- CSR build: radix partition ----
    hist1<<<NB1, 256, 0, stream>>>(ei_w, ei_c, ei_p, ei_rw, ei_rp, bh);
    int nb = (NSC + 1023) / 1024;  // 512
    scan_reduce<<<nb, 256, 0, stream>>>(bh, bsums, NSC);
    scan_bsum<<<1, 64, 0, stream>>>(bsums, nb);
    scan_final<<<nb, 256, 0, stream>>>(bh, bsums, bhscan, NSC, ETOT);
    scatter1<<<NB1, 256, 0, stream>>>(ei_w, ei_c, ei_p, ei_rw, ei_rp, bhscan, binned);
    pass2<<<256, 512, 0, stream>>>(binned, bhscan, gscan, srcs_all);

    auto PW = [&](int l, int m) { return packw + (long)(l * 8 + m) * 16384; };
    const int NT = TP + TA + TV;  // 2424
    auto GVB = [&](long n) { return (int)((n * 64 + 255) / 256); };

    auto run_layer = [&](int l, const u16* xp, const u16* xa, const u16* xv,
                         float* yfp, u16* ybp, float* yfa, u16* yba,
                         float* yfv, u16* ybv) {
        // phase BC: dual A=xp -> z3(zj0)=xp@Wl3, z4(zj2)=xp@Wl4; zas(zj1)=xa@Wr3; zvs(zj3)=xv@Wr4
        zgemm3<<<NT, 256, 0, stream>>>(xp, PW(l, 4), PW(l, 6), zj0, zj2, TP,
                                       xa, PW(l, 5), zj1, TA,
                                       xv, PW(l, 7), zj3);
        final_av<<<GVB(NAC + NVC), 256, 0, stream>>>(
            zj0, zj1, zj2, zj3, gscan + 3 * NPC, srcs_all,
            bl + (long)(l * 5 + 3) * H, bl + (long)(l * 5 + 4) * H,
            yfa, yba, yfv, ybv);
        // phase A: dual A=xp -> zps(zj0)=xp@sumWr, z1(zj2)=xp@Wl1; z0(zj1)=xa@Wl0; z2(zj3)=xv@Wl2
        zgemm3<<<NT, 256, 0, stream>>>(xp, PW(l, 3), PW(l, 1), zj0, zj2, TP,
                                       xa, PW(l, 0), zj1, TA,
                                       xv, PW(l, 2), zj3);
        final_paper<<<GVB(NPC), 256, 0, stream>>>(
            zj1, zj2, zj3, zj0, gscan, srcs_all, bsum_p + l * 128, yfp, ybp);
    };

    // layer 0: bf16 outputs staged in d_out
    run_layer(0, xpb, xab, xvb, nullptr, sp, nullptr, sa, nullptr, sv);
    // layer 1: f32 outputs into d_out (paper final last, overwrites stage after all reads)
    run_layer(1, sp, sa, sv, op, nullptr, oa, nullptr, ov, nullptr);
}